// Round 1
// baseline (49407.986 us; speedup 1.0000x reference)
//
#include <hip/hip_runtime.h>
#include <hip/hip_bf16.h>
#include <cstdint>
#include <cstddef>

#define B_ 32
#define S_ 512
#define D_ 256
#define H_ 512

#if __has_builtin(__builtin_amdgcn_exp2f)
__device__ __forceinline__ float exp2_fast(float x) { return __builtin_amdgcn_exp2f(x); }
#else
__device__ __forceinline__ float exp2_fast(float x) { return exp2f(x); }
#endif
#if __has_builtin(__builtin_amdgcn_rcpf)
__device__ __forceinline__ float rcp_fast(float x) { return __builtin_amdgcn_rcpf(x); }
#else
__device__ __forceinline__ float rcp_fast(float x) { return 1.0f / x; }
#endif

__device__ __forceinline__ float sigm(float x) {
  return rcp_fast(1.0f + exp2_fast(-1.4426950408889634f * x));
}
__device__ __forceinline__ float tanh_fast(float x) {
  // tanh(x) = 1 - 2/(exp2(2x*log2e)+1); saturates correctly at +-inf
  return 1.0f - 2.0f * rcp_fast(1.0f + exp2_fast(2.8853900817779268f * x));
}
__device__ __forceinline__ float dot4(float4 w, float4 a) {
  return w.x * a.x + w.y * a.y + w.z * a.z + w.w * a.w;
}

// One LSTM time-step, both directions (blockIdx.y: 0=fwd, 1=rev).
// Each block owns 8 h-columns (all 4 gates) for all 32 batch rows.
// z = x_t @ Wih^T + h_{t-1} @ Whh^T + b ; then fused cell update.
// h state is chained through hs[t] slots (no ping-pong buffers needed).
__global__ __launch_bounds__(256) void enc_step_k(
    const float* __restrict__ x,
    const float* __restrict__ WihF, const float* __restrict__ WhhF, const float* __restrict__ bF,
    const float* __restrict__ WihR, const float* __restrict__ WhhR, const float* __restrict__ bR,
    float* __restrict__ cF, float* __restrict__ cR,
    float* __restrict__ hsF, float* __restrict__ hsR,
    int t)
{
  const int dir = blockIdx.y;
  const float* __restrict__ Wih  = dir ? WihR : WihF;
  const float* __restrict__ Whh  = dir ? WhhR : WhhF;
  const float* __restrict__ bias = dir ? bR : bF;
  float* __restrict__ cst = dir ? cR : cF;
  float* __restrict__ hs  = dir ? hsR : hsF;
  const int xi = dir ? (S_ - 1 - t) : t;

  const int tid  = threadIdx.x;
  const int col  = tid & 31;        // gate*8 + jj
  const int gate = col >> 3;
  const int jj   = col & 7;
  const int b0   = tid >> 5;        // 0..7 -> batches b0, b0+8, b0+16, b0+24
  const int j    = (blockIdx.x << 3) + jj;
  const int wrow = gate * H_ + j;

  float acc0 = 0.f, acc1 = 0.f, acc2 = 0.f, acc3 = 0.f;

  {  // x projection part, K = D_
    const float4* __restrict__ w4 = (const float4*)(Wih + (size_t)wrow * D_);
    const float4* __restrict__ a0 = (const float4*)(x + ((size_t)(b0)      * S_ + xi) * D_);
    const float4* __restrict__ a1 = (const float4*)(x + ((size_t)(b0 + 8)  * S_ + xi) * D_);
    const float4* __restrict__ a2 = (const float4*)(x + ((size_t)(b0 + 16) * S_ + xi) * D_);
    const float4* __restrict__ a3 = (const float4*)(x + ((size_t)(b0 + 24) * S_ + xi) * D_);
    #pragma unroll 4
    for (int k = 0; k < D_ / 4; ++k) {
      float4 w = w4[k];
      acc0 += dot4(w, a0[k]);
      acc1 += dot4(w, a1[k]);
      acc2 += dot4(w, a2[k]);
      acc3 += dot4(w, a3[k]);
    }
  }
  if (t > 0) {  // recurrent part, K = H_ (h_0 == 0 so skip at t==0)
    const float* __restrict__ hprev = hs + (size_t)(dir ? xi + 1 : xi - 1) * (B_ * H_);
    const float4* __restrict__ w4 = (const float4*)(Whh + (size_t)wrow * H_);
    const float4* __restrict__ a0 = (const float4*)(hprev + (size_t)(b0)      * H_);
    const float4* __restrict__ a1 = (const float4*)(hprev + (size_t)(b0 + 8)  * H_);
    const float4* __restrict__ a2 = (const float4*)(hprev + (size_t)(b0 + 16) * H_);
    const float4* __restrict__ a3 = (const float4*)(hprev + (size_t)(b0 + 24) * H_);
    #pragma unroll 4
    for (int k = 0; k < H_ / 4; ++k) {
      float4 w = w4[k];
      acc0 += dot4(w, a0[k]);
      acc1 += dot4(w, a1[k]);
      acc2 += dot4(w, a2[k]);
      acc3 += dot4(w, a3[k]);
    }
  }

  __shared__ float shz[4][8][33];
  {
    const float bv = bias[wrow];
    shz[gate][jj][b0]      = acc0 + bv;
    shz[gate][jj][b0 + 8]  = acc1 + bv;
    shz[gate][jj][b0 + 16] = acc2 + bv;
    shz[gate][jj][b0 + 24] = acc3 + bv;
  }
  __syncthreads();

  {  // fused LSTM cell: 256 threads = 8 cols x 32 batches
    const int jj2 = tid & 7;
    const int b   = tid >> 3;
    const int jg  = (blockIdx.x << 3) + jj2;
    const float zi = shz[0][jj2][b];
    const float zf = shz[1][jj2][b];
    const float zg = shz[2][jj2][b];
    const float zo = shz[3][jj2][b];
    float* cp = cst + (size_t)b * H_ + jg;
    const float c_old = (t == 0) ? 0.f : *cp;
    const float cn = sigm(zf) * c_old + sigm(zi) * tanh_fast(zg);
    const float hn = sigm(zo) * tanh_fast(cn);
    *cp = cn;
    hs[((size_t)xi * B_ + b) * H_ + jg] = hn;
  }
}

// Decoder step: z = h_in @ Whh_d^T + b_d ; cell ; h_out = h_new (stored per-step).
__global__ __launch_bounds__(256) void dec_step_k(
    const float* __restrict__ h_in, float* __restrict__ h_out,
    float* __restrict__ c, const float* __restrict__ Whh, const float* __restrict__ bias)
{
  const int tid  = threadIdx.x;
  const int col  = tid & 31;
  const int gate = col >> 3;
  const int jj   = col & 7;
  const int b0   = tid >> 5;
  const int j    = (blockIdx.x << 3) + jj;
  const int wrow = gate * H_ + j;

  float acc0 = 0.f, acc1 = 0.f, acc2 = 0.f, acc3 = 0.f;
  {
    const float4* __restrict__ w4 = (const float4*)(Whh + (size_t)wrow * H_);
    const float4* __restrict__ a0 = (const float4*)(h_in + (size_t)(b0)      * H_);
    const float4* __restrict__ a1 = (const float4*)(h_in + (size_t)(b0 + 8)  * H_);
    const float4* __restrict__ a2 = (const float4*)(h_in + (size_t)(b0 + 16) * H_);
    const float4* __restrict__ a3 = (const float4*)(h_in + (size_t)(b0 + 24) * H_);
    #pragma unroll 4
    for (int k = 0; k < H_ / 4; ++k) {
      float4 w = w4[k];
      acc0 += dot4(w, a0[k]);
      acc1 += dot4(w, a1[k]);
      acc2 += dot4(w, a2[k]);
      acc3 += dot4(w, a3[k]);
    }
  }

  __shared__ float shz[4][8][33];
  {
    const float bv = bias[wrow];
    shz[gate][jj][b0]      = acc0 + bv;
    shz[gate][jj][b0 + 8]  = acc1 + bv;
    shz[gate][jj][b0 + 16] = acc2 + bv;
    shz[gate][jj][b0 + 24] = acc3 + bv;
  }
  __syncthreads();
  {
    const int jj2 = tid & 7;
    const int b   = tid >> 3;
    const int jg  = (blockIdx.x << 3) + jj2;
    const float zi = shz[0][jj2][b];
    const float zf = shz[1][jj2][b];
    const float zg = shz[2][jj2][b];
    const float zo = shz[3][jj2][b];
    float* cp = c + (size_t)b * H_ + jg;
    const float cn = sigm(zf) * (*cp) + sigm(zi) * tanh_fast(zg);
    const float hn = sigm(zo) * tanh_fast(cn);
    *cp = cn;
    h_out[(size_t)b * H_ + jg] = hn;
  }
}

// C[M,N] = op(A) @ Bw[N,K]^T + bias.  mode 0: A1; mode 1: A1+A2 (elementwise);
// mode 2: concat(A1,A2) along K (each with row-length K/2).
__global__ __launch_bounds__(256) void gemm_bias_k(
    const float* __restrict__ A1, const float* __restrict__ A2,
    const float* __restrict__ Bw, const float* __restrict__ bias,
    float* __restrict__ C, int M, int N, int K, int mode)
{
  const int tid   = threadIdx.x;
  const int col   = tid & 31;
  const int rg    = tid >> 5;
  const int n     = blockIdx.y * 32 + col;
  const int rbase = blockIdx.x * 64;
  float acc[8] = {0, 0, 0, 0, 0, 0, 0, 0};

  if (mode == 2) {
    const int K1 = K >> 1;
    const float4* __restrict__ w4 = (const float4*)(Bw + (size_t)n * K);
    for (int pass = 0; pass < 2; ++pass) {
      const float* __restrict__ A = pass ? A2 : A1;
      const float4* __restrict__ wp = w4 + pass * (K1 >> 2);
      for (int k = 0; k < (K1 >> 2); ++k) {
        float4 w = wp[k];
        #pragma unroll
        for (int i = 0; i < 8; ++i) {
          int r = rbase + rg + (i << 3);
          if (r < M) acc[i] += dot4(w, ((const float4*)(A + (size_t)r * K1))[k]);
        }
      }
    }
  } else if (mode == 1) {
    const float4* __restrict__ w4 = (const float4*)(Bw + (size_t)n * K);
    for (int k = 0; k < (K >> 2); ++k) {
      float4 w = w4[k];
      #pragma unroll
      for (int i = 0; i < 8; ++i) {
        int r = rbase + rg + (i << 3);
        float4 a  = ((const float4*)(A1 + (size_t)r * K))[k];
        float4 a2 = ((const float4*)(A2 + (size_t)r * K))[k];
        a.x += a2.x; a.y += a2.y; a.z += a2.z; a.w += a2.w;
        acc[i] += dot4(w, a);
      }
    }
  } else {
    const float4* __restrict__ w4 = (const float4*)(Bw + (size_t)n * K);
    for (int k = 0; k < (K >> 2); ++k) {
      float4 w = w4[k];
      #pragma unroll
      for (int i = 0; i < 8; ++i) {
        int r = rbase + rg + (i << 3);
        acc[i] += dot4(w, ((const float4*)(A1 + (size_t)r * K))[k]);
      }
    }
  }

  const float bv = bias[n];
  #pragma unroll
  for (int i = 0; i < 8; ++i) {
    int r = rbase + rg + (i << 3);
    if (r < M) C[(size_t)r * N + n] = acc[i] + bv;
  }
}

// logits[b, t, s] = bvt + sum_h vt[h] * tanh(pre1[s,b,h] + Q[t,b,h])
#define ACH 256
__global__ __launch_bounds__(256) void attn_k(
    const float* __restrict__ pre1, const float* __restrict__ Qm,
    const float* __restrict__ vt, const float* __restrict__ bvt,
    float* __restrict__ out)
{
  __shared__ float sp[16][ACH + 4];
  __shared__ float sq[16][ACH + 4];
  __shared__ float sv[ACH];
  const int b     = blockIdx.z;
  const int tbase = blockIdx.y << 4;
  const int sbase = blockIdx.x << 4;
  const int tid   = threadIdx.x;
  const int so    = tid & 15;   // s offset (fast -> coalesced out writes)
  const int to    = tid >> 4;   // t offset
  float acc = 0.f;

  for (int h0 = 0; h0 < H_; h0 += ACH) {
    __syncthreads();
    #pragma unroll
    for (int u = 0; u < (16 * ACH) / 256; ++u) {
      int idx = tid + u * 256;
      int i = idx >> 8;          // ACH == 256
      int h = idx & (ACH - 1);
      sq[i][h] = Qm[((size_t)(tbase + i) * B_ + b) * H_ + h0 + h];
      sp[i][h] = pre1[((size_t)(sbase + i) * B_ + b) * H_ + h0 + h];
    }
    if (tid < ACH) sv[tid] = vt[h0 + tid];
    __syncthreads();
    #pragma unroll 4
    for (int h = 0; h < ACH; ++h)
      acc += sv[h] * tanh_fast(sp[so][h] + sq[to][h]);
  }
  out[((size_t)b * S_ + tbase + to) * S_ + sbase + so] = acc + bvt[0];
}

extern "C" void kernel_launch(void* const* d_in, const int* in_sizes, int n_in,
                              void* d_out, int out_size, void* d_ws, size_t ws_size,
                              hipStream_t stream)
{
  (void)in_sizes; (void)n_in; (void)out_size; (void)ws_size;
  const float* x     = (const float*)d_in[0];
  const float* WihF  = (const float*)d_in[1];
  const float* WhhF  = (const float*)d_in[2];
  const float* bF    = (const float*)d_in[3];
  const float* WihR  = (const float*)d_in[4];
  const float* WhhR  = (const float*)d_in[5];
  const float* bR    = (const float*)d_in[6];
  /* d_in[7] = Wih_d is unused by the reference decoder */
  const float* WhhD  = (const float*)d_in[8];
  const float* bD    = (const float*)d_in[9];
  const float* Wr_h  = (const float*)d_in[10];
  const float* br_h  = (const float*)d_in[11];
  const float* Wr_c  = (const float*)d_in[12];
  const float* br_c  = (const float*)d_in[13];
  const float* W1    = (const float*)d_in[14];
  const float* b1    = (const float*)d_in[15];
  const float* W2    = (const float*)d_in[16];
  const float* b2    = (const float*)d_in[17];
  const float* vt    = (const float*)d_in[18];
  const float* bvt   = (const float*)d_in[19];
  float* out = (float*)d_out;
  float* ws  = (float*)d_ws;

  const size_t SBH = (size_t)S_ * B_ * H_;   // 8,388,608 floats
  const size_t BH  = (size_t)B_ * H_;        // 16,384 floats

  float* hs_f = ws;                 // [S,B,H]
  float* hs_r = ws + SBH;           // [S,B,H]
  float* pre1 = ws + 2 * SBH;       // [S,B,H]
  float* cF   = ws + 3 * SBH;       // [B,H]
  float* cR   = cF + BH;            // [B,H]
  float* cD   = cR + BH;            // [B,H]
  float* hd0  = cD + BH;            // [B,H]
  float* hdec = hs_f;               // reuse: dead after pre1 GEMM
  float* Qm   = hs_r;               // reuse: dead after pre1 GEMM

  // ---- encoder: 512 steps, fwd+rev fused (grid.y = 2) ----
  for (int t = 0; t < S_; ++t)
    enc_step_k<<<dim3(64, 2), 256, 0, stream>>>(x, WihF, WhhF, bF, WihR, WhhR, bR,
                                                cF, cR, hs_f, hs_r, t);

  // ---- decoder init: h_d = [hf|hr]@Wr_h^T + br_h ; c_d likewise ----
  gemm_bias_k<<<dim3(1, 16), 256, 0, stream>>>(hs_f + (size_t)(S_ - 1) * BH, hs_r,
                                               Wr_h, br_h, hd0, B_, H_, 2 * H_, 2);
  gemm_bias_k<<<dim3(1, 16), 256, 0, stream>>>(cF, cR, Wr_c, br_c, cD, B_, H_, 2 * H_, 2);

  // ---- pre1 = (hs_f + hs_r) @ W1^T + b1 ----
  gemm_bias_k<<<dim3(256, 16), 256, 0, stream>>>(hs_f, hs_r, W1, b1, pre1,
                                                 S_ * B_, H_, H_, 1);

  // ---- decoder recurrence (attention deferred) ----
  for (int t = 0; t < S_; ++t)
    dec_step_k<<<64, 256, 0, stream>>>(t == 0 ? hd0 : hdec + (size_t)(t - 1) * BH,
                                       hdec + (size_t)t * BH, cD, WhhD, bD);

  // ---- Q = Hdec @ W2^T + b2 ----
  gemm_bias_k<<<dim3(256, 16), 256, 0, stream>>>(hdec, nullptr, W2, b2, Qm,
                                                 S_ * B_, H_, H_, 0);

  // ---- attention: logits[b,t,s] ----
  attn_k<<<dim3(32, 32, 32), 256, 0, stream>>>(pre1, Qm, vt, bvt, out);
}

// Round 2
// 30516.562 us; speedup vs baseline: 1.6191x; 1.6191x over previous
//
#include <hip/hip_runtime.h>
#include <hip/hip_bf16.h>
#include <cstdint>
#include <cstddef>

#define B_ 32
#define S_ 512
#define D_ 256
#define H_ 512

#define NBLK_ENC 256
#define NBLK_DEC 128

#if __has_builtin(__builtin_amdgcn_exp2f)
__device__ __forceinline__ float exp2_fast(float x) { return __builtin_amdgcn_exp2f(x); }
#else
__device__ __forceinline__ float exp2_fast(float x) { return exp2f(x); }
#endif
#if __has_builtin(__builtin_amdgcn_rcpf)
__device__ __forceinline__ float rcp_fast(float x) { return __builtin_amdgcn_rcpf(x); }
#else
__device__ __forceinline__ float rcp_fast(float x) { return 1.0f / x; }
#endif

__device__ __forceinline__ float sigm(float x) {
  return rcp_fast(1.0f + exp2_fast(-1.4426950408889634f * x));
}
__device__ __forceinline__ float tanh_fast(float x) {
  return 1.0f - 2.0f * rcp_fast(1.0f + exp2_fast(2.8853900817779268f * x));
}
__device__ __forceinline__ float dot4(float4 w, float4 a) {
  return w.x * a.x + w.y * a.y + w.z * a.z + w.w * a.w;
}

// Device-scope grid barrier: monotonic counter in global ws (zeroed per launch).
// Release: __syncthreads (drains block's vmem) + thread0 threadfence (L2 wb) + atomic add.
// Acquire: spin on agent-scope load, then threadfence (cache inv) + __syncthreads.
__device__ __forceinline__ void grid_sync(int* bar, int target) {
  __syncthreads();
  if (threadIdx.x == 0) {
    __threadfence();
    __hip_atomic_fetch_add(bar, 1, __ATOMIC_RELAXED, __HIP_MEMORY_SCOPE_AGENT);
    while (__hip_atomic_load(bar, __ATOMIC_RELAXED, __HIP_MEMORY_SCOPE_AGENT) < target)
      __builtin_amdgcn_s_sleep(1);
    __threadfence();
  }
  __syncthreads();
}

// Persistent encoder: 256 blocks (128 fwd + 128 rev), 512 steps in-kernel.
// Block owns 4 h-cols x 4 gates = 16 wrows; weights preloaded to LDS once.
__global__ __launch_bounds__(256) void enc_coop_k(
    const float* __restrict__ x,
    const float* __restrict__ WihF, const float* __restrict__ WhhF, const float* __restrict__ bF,
    const float* __restrict__ WihR, const float* __restrict__ WhhR, const float* __restrict__ bR,
    float* __restrict__ cF, float* __restrict__ cR,
    float* __restrict__ hsF, float* __restrict__ hsR,
    int* __restrict__ bar)
{
  __shared__ __align__(16) float whh[16][516];  // +4 pad: <=2-way bank conflict on b128
  __shared__ __align__(16) float wih[16][260];
  __shared__ float zb[16][33];
  __shared__ float cst[4][33];

  const int bid = blockIdx.x;
  const int dir = bid >> 7;
  const int jb  = bid & 127;
  const int j0  = jb << 2;
  const int tid = threadIdx.x;

  const float* __restrict__ Wih  = dir ? WihR : WihF;
  const float* __restrict__ Whh  = dir ? WhhR : WhhF;
  const float* __restrict__ bias = dir ? bR : bF;
  float* __restrict__ hs   = dir ? hsR : hsF;
  float* __restrict__ cOut = dir ? cR : cF;

  for (int idx = tid; idx < 16 * 128; idx += 256) {
    int r = idx >> 7, k4 = idx & 127;
    int g = r >> 2, jc = r & 3;
    float4 w = *(const float4*)(Whh + ((size_t)(g * H_ + j0 + jc)) * H_ + k4 * 4);
    *(float4*)(&whh[r][k4 * 4]) = w;
  }
  for (int idx = tid; idx < 16 * 64; idx += 256) {
    int r = idx >> 6, k4 = idx & 63;
    int g = r >> 2, jc = r & 3;
    float4 w = *(const float4*)(Wih + ((size_t)(g * H_ + j0 + jc)) * D_ + k4 * 4);
    *(float4*)(&wih[r][k4 * 4]) = w;
  }

  const int r  = tid & 15;   // wrow within block
  const int bp = tid >> 4;   // batch pair: handles batches bp and bp+16
  const int g  = r >> 2, jc = r & 3;
  const float bv = bias[g * H_ + j0 + jc];
  __syncthreads();

  int target = 0;
  for (int t = 0; t < S_; ++t) {
    const int xi = dir ? (S_ - 1 - t) : t;
    float acc0 = bv, acc1 = bv;
    {
      const float4* __restrict__ a0 = (const float4*)(x + ((size_t)bp * S_ + xi) * D_);
      const float4* __restrict__ a1 = (const float4*)(x + ((size_t)(bp + 16) * S_ + xi) * D_);
      #pragma unroll 4
      for (int k4 = 0; k4 < 64; ++k4) {
        float4 w = *(const float4*)(&wih[r][k4 * 4]);
        acc0 += dot4(w, a0[k4]);
        acc1 += dot4(w, a1[k4]);
      }
    }
    if (t > 0) {
      const float* __restrict__ hp = hs + (size_t)(dir ? xi + 1 : xi - 1) * (B_ * H_);
      const float4* __restrict__ a0 = (const float4*)(hp + (size_t)bp * H_);
      const float4* __restrict__ a1 = (const float4*)(hp + (size_t)(bp + 16) * H_);
      #pragma unroll 4
      for (int k4 = 0; k4 < 128; ++k4) {
        float4 w = *(const float4*)(&whh[r][k4 * 4]);
        acc0 += dot4(w, a0[k4]);
        acc1 += dot4(w, a1[k4]);
      }
    }
    zb[r][bp]      = acc0;
    zb[r][bp + 16] = acc1;
    __syncthreads();
    if (tid < 128) {
      const int jc2 = tid >> 5, b = tid & 31;
      const float zi = zb[jc2][b];
      const float zf = zb[4 + jc2][b];
      const float zg = zb[8 + jc2][b];
      const float zo = zb[12 + jc2][b];
      const float c_old = (t == 0) ? 0.f : cst[jc2][b];
      const float cn = sigm(zf) * c_old + sigm(zi) * tanh_fast(zg);
      const float hn = sigm(zo) * tanh_fast(cn);
      cst[jc2][b] = cn;
      hs[((size_t)xi * B_ + b) * H_ + j0 + jc2] = hn;
      if (t == S_ - 1) cOut[(size_t)b * H_ + j0 + jc2] = cn;
    }
    target += NBLK_ENC;
    if (t != S_ - 1) grid_sync(bar, target);
  }
}

// Persistent decoder: 128 blocks, 512 steps. z = h@WhhD^T + b_d only.
__global__ __launch_bounds__(256) void dec_coop_k(
    const float* __restrict__ hd0, const float* __restrict__ cD0,
    const float* __restrict__ Whh, const float* __restrict__ bias,
    float* __restrict__ hdec, int* __restrict__ bar)
{
  __shared__ __align__(16) float whh[16][516];
  __shared__ float zb[16][33];
  __shared__ float cst[4][33];

  const int bid = blockIdx.x;
  const int j0  = bid << 2;
  const int tid = threadIdx.x;

  for (int idx = tid; idx < 16 * 128; idx += 256) {
    int r = idx >> 7, k4 = idx & 127;
    int g = r >> 2, jc = r & 3;
    float4 w = *(const float4*)(Whh + ((size_t)(g * H_ + j0 + jc)) * H_ + k4 * 4);
    *(float4*)(&whh[r][k4 * 4]) = w;
  }
  if (tid < 128) {
    const int jc2 = tid >> 5, b = tid & 31;
    cst[jc2][b] = cD0[(size_t)b * H_ + j0 + jc2];
  }

  const int r  = tid & 15;
  const int bp = tid >> 4;
  const int g  = r >> 2, jc = r & 3;
  const float bv = bias[g * H_ + j0 + jc];
  __syncthreads();

  int target = 0;
  for (int t = 0; t < S_; ++t) {
    const float* __restrict__ hp = (t == 0) ? hd0 : (hdec + (size_t)(t - 1) * (B_ * H_));
    float acc0 = bv, acc1 = bv;
    {
      const float4* __restrict__ a0 = (const float4*)(hp + (size_t)bp * H_);
      const float4* __restrict__ a1 = (const float4*)(hp + (size_t)(bp + 16) * H_);
      #pragma unroll 4
      for (int k4 = 0; k4 < 128; ++k4) {
        float4 w = *(const float4*)(&whh[r][k4 * 4]);
        acc0 += dot4(w, a0[k4]);
        acc1 += dot4(w, a1[k4]);
      }
    }
    zb[r][bp]      = acc0;
    zb[r][bp + 16] = acc1;
    __syncthreads();
    if (tid < 128) {
      const int jc2 = tid >> 5, b = tid & 31;
      const float zi = zb[jc2][b];
      const float zf = zb[4 + jc2][b];
      const float zg = zb[8 + jc2][b];
      const float zo = zb[12 + jc2][b];
      const float cn = sigm(zf) * cst[jc2][b] + sigm(zi) * tanh_fast(zg);
      const float hn = sigm(zo) * tanh_fast(cn);
      cst[jc2][b] = cn;
      hdec[((size_t)t * B_ + b) * H_ + j0 + jc2] = hn;
    }
    target += NBLK_DEC;
    if (t != S_ - 1) grid_sync(bar, target);
  }
}

// C[M,N] = op(A) @ Bw[N,K]^T + bias.  mode 0: A1; mode 1: A1+A2; mode 2: concat K.
__global__ __launch_bounds__(256) void gemm_bias_k(
    const float* __restrict__ A1, const float* __restrict__ A2,
    const float* __restrict__ Bw, const float* __restrict__ bias,
    float* __restrict__ C, int M, int N, int K, int mode)
{
  const int tid   = threadIdx.x;
  const int col   = tid & 31;
  const int rg    = tid >> 5;
  const int n     = blockIdx.y * 32 + col;
  const int rbase = blockIdx.x * 64;
  float acc[8] = {0, 0, 0, 0, 0, 0, 0, 0};

  if (mode == 2) {
    const int K1 = K >> 1;
    const float4* __restrict__ w4 = (const float4*)(Bw + (size_t)n * K);
    for (int pass = 0; pass < 2; ++pass) {
      const float* __restrict__ A = pass ? A2 : A1;
      const float4* __restrict__ wp = w4 + pass * (K1 >> 2);
      for (int k = 0; k < (K1 >> 2); ++k) {
        float4 w = wp[k];
        #pragma unroll
        for (int i = 0; i < 8; ++i) {
          int rr = rbase + rg + (i << 3);
          if (rr < M) acc[i] += dot4(w, ((const float4*)(A + (size_t)rr * K1))[k]);
        }
      }
    }
  } else if (mode == 1) {
    const float4* __restrict__ w4 = (const float4*)(Bw + (size_t)n * K);
    for (int k = 0; k < (K >> 2); ++k) {
      float4 w = w4[k];
      #pragma unroll
      for (int i = 0; i < 8; ++i) {
        int rr = rbase + rg + (i << 3);
        float4 a  = ((const float4*)(A1 + (size_t)rr * K))[k];
        float4 a2 = ((const float4*)(A2 + (size_t)rr * K))[k];
        a.x += a2.x; a.y += a2.y; a.z += a2.z; a.w += a2.w;
        acc[i] += dot4(w, a);
      }
    }
  } else {
    const float4* __restrict__ w4 = (const float4*)(Bw + (size_t)n * K);
    for (int k = 0; k < (K >> 2); ++k) {
      float4 w = w4[k];
      #pragma unroll
      for (int i = 0; i < 8; ++i) {
        int rr = rbase + rg + (i << 3);
        acc[i] += dot4(w, ((const float4*)(A1 + (size_t)rr * K))[k]);
      }
    }
  }

  const float bv = bias[n];
  #pragma unroll
  for (int i = 0; i < 8; ++i) {
    int rr = rbase + rg + (i << 3);
    if (rr < M) C[(size_t)rr * N + n] = acc[i] + bv;
  }
}

// logits[b, t, s] = bvt + sum_h vt[h] * tanh(pre1[s,b,h] + Q[t,b,h])
#define ACH 256
__global__ __launch_bounds__(256) void attn_k(
    const float* __restrict__ pre1, const float* __restrict__ Qm,
    const float* __restrict__ vt, const float* __restrict__ bvt,
    float* __restrict__ out)
{
  __shared__ float sp[16][ACH + 4];
  __shared__ float sq[16][ACH + 4];
  __shared__ float sv[ACH];
  const int b     = blockIdx.z;
  const int tbase = blockIdx.y << 4;
  const int sbase = blockIdx.x << 4;
  const int tid   = threadIdx.x;
  const int so    = tid & 15;
  const int to    = tid >> 4;
  float acc = 0.f;

  for (int h0 = 0; h0 < H_; h0 += ACH) {
    __syncthreads();
    #pragma unroll
    for (int u = 0; u < (16 * ACH) / 256; ++u) {
      int idx = tid + u * 256;
      int i = idx >> 8;
      int h = idx & (ACH - 1);
      sq[i][h] = Qm[((size_t)(tbase + i) * B_ + b) * H_ + h0 + h];
      sp[i][h] = pre1[((size_t)(sbase + i) * B_ + b) * H_ + h0 + h];
    }
    if (tid < ACH) sv[tid] = vt[h0 + tid];
    __syncthreads();
    #pragma unroll 4
    for (int h = 0; h < ACH; ++h)
      acc += sv[h] * tanh_fast(sp[so][h] + sq[to][h]);
  }
  out[((size_t)b * S_ + tbase + to) * S_ + sbase + so] = acc + bvt[0];
}

extern "C" void kernel_launch(void* const* d_in, const int* in_sizes, int n_in,
                              void* d_out, int out_size, void* d_ws, size_t ws_size,
                              hipStream_t stream)
{
  (void)in_sizes; (void)n_in; (void)out_size; (void)ws_size;
  const float* x     = (const float*)d_in[0];
  const float* WihF  = (const float*)d_in[1];
  const float* WhhF  = (const float*)d_in[2];
  const float* bF    = (const float*)d_in[3];
  const float* WihR  = (const float*)d_in[4];
  const float* WhhR  = (const float*)d_in[5];
  const float* bR    = (const float*)d_in[6];
  /* d_in[7] = Wih_d unused by reference decoder */
  const float* WhhD  = (const float*)d_in[8];
  const float* bD    = (const float*)d_in[9];
  const float* Wr_h  = (const float*)d_in[10];
  const float* br_h  = (const float*)d_in[11];
  const float* Wr_c  = (const float*)d_in[12];
  const float* br_c  = (const float*)d_in[13];
  const float* W1    = (const float*)d_in[14];
  const float* b1    = (const float*)d_in[15];
  const float* W2    = (const float*)d_in[16];
  const float* b2    = (const float*)d_in[17];
  const float* vt    = (const float*)d_in[18];
  const float* bvt   = (const float*)d_in[19];
  float* out = (float*)d_out;
  float* ws  = (float*)d_ws;

  const size_t SBH = (size_t)S_ * B_ * H_;
  const size_t BH  = (size_t)B_ * H_;

  float* hs_f = ws;
  float* hs_r = ws + SBH;
  float* pre1 = ws + 2 * SBH;
  float* cF   = ws + 3 * SBH;
  float* cR   = cF + BH;
  float* cD   = cR + BH;
  float* hd0  = cD + BH;
  int*   bars = (int*)(ws + 3 * SBH + 4 * BH);
  float* hdec = hs_f;   // reuse after pre1
  float* Qm   = hs_r;   // reuse after pre1

  hipMemsetAsync(bars, 0, 256, stream);

  // ---- encoder: persistent, both dirs, 512 steps in-kernel ----
  enc_coop_k<<<NBLK_ENC, 256, 0, stream>>>(x, WihF, WhhF, bF, WihR, WhhR, bR,
                                           cF, cR, hs_f, hs_r, bars);

  // ---- decoder init ----
  gemm_bias_k<<<dim3(1, 16), 256, 0, stream>>>(hs_f + (size_t)(S_ - 1) * BH, hs_r,
                                               Wr_h, br_h, hd0, B_, H_, 2 * H_, 2);
  gemm_bias_k<<<dim3(1, 16), 256, 0, stream>>>(cF, cR, Wr_c, br_c, cD, B_, H_, 2 * H_, 2);

  // ---- pre1 = (hs_f + hs_r) @ W1^T + b1 ----
  gemm_bias_k<<<dim3(256, 16), 256, 0, stream>>>(hs_f, hs_r, W1, b1, pre1,
                                                 S_ * B_, H_, H_, 1);

  // ---- decoder: persistent, 512 steps in-kernel ----
  dec_coop_k<<<NBLK_DEC, 256, 0, stream>>>(hd0, cD, WhhD, bD, hdec, bars + 32);

  // ---- Q = Hdec @ W2^T + b2 ----
  gemm_bias_k<<<dim3(256, 16), 256, 0, stream>>>(hdec, nullptr, W2, b2, Qm,
                                                 S_ * B_, H_, H_, 0);

  // ---- attention ----
  attn_k<<<dim3(32, 32, 32), 256, 0, stream>>>(pre1, Qm, vt, bvt, out);
}

// Round 3
// 18603.337 us; speedup vs baseline: 2.6559x; 1.6404x over previous
//
#include <hip/hip_runtime.h>
#include <hip/hip_bf16.h>
#include <cstdint>
#include <cstddef>

#define B_ 32
#define S_ 512
#define D_ 256
#define H_ 512

#if __has_builtin(__builtin_amdgcn_exp2f)
__device__ __forceinline__ float exp2_fast(float x) { return __builtin_amdgcn_exp2f(x); }
#else
__device__ __forceinline__ float exp2_fast(float x) { return exp2f(x); }
#endif
#if __has_builtin(__builtin_amdgcn_rcpf)
__device__ __forceinline__ float rcp_fast(float x) { return __builtin_amdgcn_rcpf(x); }
#else
__device__ __forceinline__ float rcp_fast(float x) { return 1.0f / x; }
#endif

__device__ __forceinline__ float sigm(float x) {
  return rcp_fast(1.0f + exp2_fast(-1.4426950408889634f * x));
}
__device__ __forceinline__ float tanh_fast(float x) {
  return 1.0f - 2.0f * rcp_fast(1.0f + exp2_fast(2.8853900817779268f * x));
}
__device__ __forceinline__ float dot4(float4 w, float4 a) {
  return w.x * a.x + w.y * a.y + w.z * a.z + w.w * a.w;
}

// Coherent (L3-backed) float store/load: bypass stale L1/L2 cross-XCD.
__device__ __forceinline__ void coh_store(float* p, float v) {
  __hip_atomic_store(p, v, __ATOMIC_RELAXED, __HIP_MEMORY_SCOPE_AGENT);
}
__device__ __forceinline__ float2 coh_load2(const float* p) {
  unsigned long long v = __hip_atomic_load((const unsigned long long*)p,
                                           __ATOMIC_RELAXED, __HIP_MEMORY_SCOPE_AGENT);
  float2 f;
  __builtin_memcpy(&f, &v, 8);
  return f;
}

// Group barrier. Stores preceding this are sc1 write-through and drained by the
// vmcnt(0) inside __syncthreads, so a relaxed add suffices (no L2 inv/wb!).
__device__ __forceinline__ void group_sync(int* bar, int target) {
  __syncthreads();
  if (threadIdx.x == 0) {
    __hip_atomic_fetch_add(bar, 1, __ATOMIC_RELAXED, __HIP_MEMORY_SCOPE_AGENT);
    while (__hip_atomic_load(bar, __ATOMIC_RELAXED, __HIP_MEMORY_SCOPE_AGENT) < target)
      __builtin_amdgcn_s_sleep(2);
  }
  __syncthreads();
}

// ---------------- persistent encoder ----------------
// 256 blocks = 4 groups (dir x 16-batch half) x 64 blocks.
// Block: 32 wrows (8 h-cols x 4 gates), Whh rows in LDS (fp32), h staged per step.
__global__ __launch_bounds__(256) void enc_coop_k(
    const float* __restrict__ x,
    const float* __restrict__ WihF, const float* __restrict__ WhhF, const float* __restrict__ bF,
    const float* __restrict__ WihR, const float* __restrict__ WhhR, const float* __restrict__ bR,
    float* __restrict__ cF, float* __restrict__ cR,
    float* __restrict__ hsF, float* __restrict__ hsR,
    int* __restrict__ bars)
{
  __shared__ __align__(16) float whh[32][516];   // 66 KB, +4 pad: conflict-free
  __shared__ __align__(16) float hbuf[16][516];  // 33 KB staged h (group's 16 batches)
  __shared__ float zb[32][17];
  __shared__ float cls[8][17];

  const int bid   = blockIdx.x;
  const int group = bid >> 6;        // 0..3
  const int dir   = group >> 1;
  const int bg    = group & 1;       // batch half: batches bg*16 .. +15
  const int jb    = bid & 63;
  const int c0    = jb << 3;         // 8 h-cols per block
  const int tid   = threadIdx.x;

  const float* __restrict__ Wih  = dir ? WihR : WihF;
  const float* __restrict__ Whh  = dir ? WhhR : WhhF;
  const float* __restrict__ bias = dir ? bR : bF;
  float* __restrict__ hs   = dir ? hsR : hsF;
  float* __restrict__ cOut = dir ? cR : cF;
  int* bar = bars + group * 32;

  // preload Whh rows (32 x 512) into LDS
  for (int idx = tid; idx < 32 * 128; idx += 256) {
    int r = idx >> 7, k4 = idx & 127;
    int wrow = (r >> 3) * H_ + c0 + (r & 7);
    *(float4*)(&whh[r][k4 * 4]) = *(const float4*)(Whh + (size_t)wrow * H_ + k4 * 4);
  }

  const int r  = tid >> 3;          // 0..31: this thread's wrow
  const int bs = tid & 7;           // batches bs and bs+8 within group
  const int wrow = (r >> 3) * H_ + c0 + (r & 7);
  const float bv = bias[wrow];
  const int gb0 = bg * 16 + bs;
  const int gb1 = gb0 + 8;
  const float4* __restrict__ wih4 = (const float4*)(Wih + (size_t)wrow * D_);
  __syncthreads();

  int target = 0;
  for (int t = 0; t < S_; ++t) {
    const int xi = dir ? (S_ - 1 - t) : t;
    float acc0 = bv, acc1 = bv;
    {  // x part (K=256), Wih/x via normal cached loads (read-only)
      const float4* __restrict__ a0 = (const float4*)(x + ((size_t)gb0 * S_ + xi) * D_);
      const float4* __restrict__ a1 = (const float4*)(x + ((size_t)gb1 * S_ + xi) * D_);
      #pragma unroll 4
      for (int k4 = 0; k4 < 64; ++k4) {
        float4 w = wih4[k4];
        acc0 += dot4(w, a0[k4]);
        acc1 += dot4(w, a1[k4]);
      }
    }
    if (t > 0) {  // h part (K=512) from LDS
      const float4* __restrict__ h0 = (const float4*)(&hbuf[bs][0]);
      const float4* __restrict__ h1 = (const float4*)(&hbuf[bs + 8][0]);
      #pragma unroll 4
      for (int k4 = 0; k4 < 128; ++k4) {
        float4 w = *(const float4*)(&whh[r][k4 * 4]);
        acc0 += dot4(w, h0[k4]);
        acc1 += dot4(w, h1[k4]);
      }
    }
    zb[r][bs]     = acc0;
    zb[r][bs + 8] = acc1;
    __syncthreads();

    if (tid < 128) {  // cell: 8 cols x 16 batches
      const int cc = tid >> 4, b = tid & 15;
      const float zi = zb[cc][b];
      const float zf = zb[8 + cc][b];
      const float zg = zb[16 + cc][b];
      const float zo = zb[24 + cc][b];
      const float c_old = (t == 0) ? 0.f : cls[cc][b];
      const float cn = sigm(zf) * c_old + sigm(zi) * tanh_fast(zg);
      const float hn = sigm(zo) * tanh_fast(cn);
      cls[cc][b] = cn;
      const int gb = bg * 16 + b;
      coh_store(&hs[((size_t)xi * B_ + gb) * H_ + c0 + cc], hn);
      if (t == S_ - 1) cOut[(size_t)gb * H_ + c0 + cc] = cn;
    }

    if (t == S_ - 1) break;
    target += 64;
    group_sync(bar, target);

    // stage h[xi] (just produced by whole group) into LDS: 16 x 512 floats
    #pragma unroll
    for (int i = 0; i < 16; ++i) {
      int idx = tid + i * 256;
      int b = idx >> 8, k2 = idx & 255;
      float2 v = coh_load2(&hs[((size_t)xi * B_ + bg * 16 + b) * H_ + k2 * 2]);
      *(float2*)(&hbuf[b][k2 * 2]) = v;
    }
    __syncthreads();
  }
}

// ---------------- persistent decoder ----------------
// 256 blocks = 4 groups (8 batches) x 64 blocks; block: 32 wrows.
__global__ __launch_bounds__(256) void dec_coop_k(
    const float* __restrict__ hd0, const float* __restrict__ cD0,
    const float* __restrict__ Whh, const float* __restrict__ bias,
    float* __restrict__ hdec, int* __restrict__ bars)
{
  __shared__ __align__(16) float whh[32][516];
  __shared__ __align__(16) float hbuf[8][516];
  __shared__ float zb[32][9];
  __shared__ float cls[8][9];

  const int bid   = blockIdx.x;
  const int group = bid >> 6;        // 0..3: batches group*8 .. +7
  const int jb    = bid & 63;
  const int c0    = jb << 3;
  const int tid   = threadIdx.x;
  int* bar = bars + (4 + group) * 32;

  for (int idx = tid; idx < 32 * 128; idx += 256) {
    int r = idx >> 7, k4 = idx & 127;
    int wrow = (r >> 3) * H_ + c0 + (r & 7);
    *(float4*)(&whh[r][k4 * 4]) = *(const float4*)(Whh + (size_t)wrow * H_ + k4 * 4);
  }
  // stage hd0 (8 batches x 512) + init c
  #pragma unroll
  for (int i = 0; i < 8; ++i) {
    int idx = tid + i * 256;
    int b = idx >> 8, k2 = idx & 255;
    *(float2*)(&hbuf[b][k2 * 2]) =
        *(const float2*)(hd0 + ((size_t)(group * 8 + b)) * H_ + k2 * 2);
  }
  if (tid < 64) {
    const int cc = tid >> 3, b = tid & 7;
    cls[cc][b] = cD0[(size_t)(group * 8 + b) * H_ + c0 + cc];
  }

  const int r  = tid >> 3;
  const int bs = tid & 7;            // 1 batch per thread
  const int wrow = (r >> 3) * H_ + c0 + (r & 7);
  const float bv = bias[wrow];
  __syncthreads();

  int target = 0;
  for (int t = 0; t < S_; ++t) {
    float acc0 = bv;
    {
      const float4* __restrict__ h0 = (const float4*)(&hbuf[bs][0]);
      #pragma unroll 4
      for (int k4 = 0; k4 < 128; ++k4) {
        float4 w = *(const float4*)(&whh[r][k4 * 4]);
        acc0 += dot4(w, h0[k4]);
      }
    }
    zb[r][bs] = acc0;
    __syncthreads();

    if (tid < 64) {
      const int cc = tid >> 3, b = tid & 7;
      const float zi = zb[cc][b];
      const float zf = zb[8 + cc][b];
      const float zg = zb[16 + cc][b];
      const float zo = zb[24 + cc][b];
      const float cn = sigm(zf) * cls[cc][b] + sigm(zi) * tanh_fast(zg);
      const float hn = sigm(zo) * tanh_fast(cn);
      cls[cc][b] = cn;
      coh_store(&hdec[((size_t)t * B_ + group * 8 + b) * H_ + c0 + cc], hn);
    }

    if (t == S_ - 1) break;
    target += 64;
    group_sync(bar, target);

    #pragma unroll
    for (int i = 0; i < 8; ++i) {
      int idx = tid + i * 256;
      int b = idx >> 8, k2 = idx & 255;
      float2 v = coh_load2(&hdec[((size_t)t * B_ + group * 8 + b) * H_ + k2 * 2]);
      *(float2*)(&hbuf[b][k2 * 2]) = v;
    }
    __syncthreads();
  }
}

// ---------------- tiled fp32 GEMM: C[M,512] = op(A)@W^T + bias ----------------
// MODE 0: A1 ; MODE 1: A1 + A2 (elementwise). 64x64 tile, K-chunk 32.
template <int MODE>
__global__ __launch_bounds__(256) void gemm_tiled_k(
    const float* __restrict__ A1, const float* __restrict__ A2,
    const float* __restrict__ W, const float* __restrict__ bias,
    float* __restrict__ C)
{
  __shared__ float As[32][68];  // [k][m]
  __shared__ float Bs[32][68];  // [k][n]
  const int tid = threadIdx.x;
  const int m0 = blockIdx.x * 64, n0 = blockIdx.y * 64;
  const int tn = tid & 15, tm = tid >> 4;
  float acc[4][4] = {};

  for (int kc = 0; kc < H_; kc += 32) {
    __syncthreads();
    #pragma unroll
    for (int u = 0; u < 2; ++u) {
      int idx = tid + u * 256;
      int mm = idx >> 3, kk = (idx & 7) << 2;
      float4 a = *(const float4*)(A1 + (size_t)(m0 + mm) * H_ + kc + kk);
      if (MODE == 1) {
        float4 a2 = *(const float4*)(A2 + (size_t)(m0 + mm) * H_ + kc + kk);
        a.x += a2.x; a.y += a2.y; a.z += a2.z; a.w += a2.w;
      }
      As[kk][mm] = a.x; As[kk + 1][mm] = a.y; As[kk + 2][mm] = a.z; As[kk + 3][mm] = a.w;
      float4 b = *(const float4*)(W + (size_t)(n0 + mm) * H_ + kc + kk);
      Bs[kk][mm] = b.x; Bs[kk + 1][mm] = b.y; Bs[kk + 2][mm] = b.z; Bs[kk + 3][mm] = b.w;
    }
    __syncthreads();
    #pragma unroll 8
    for (int k = 0; k < 32; ++k) {
      float4 av = *(const float4*)(&As[k][tm * 4]);
      float4 bv = *(const float4*)(&Bs[k][tn * 4]);
      float ar[4] = {av.x, av.y, av.z, av.w};
      float br[4] = {bv.x, bv.y, bv.z, bv.w};
      #pragma unroll
      for (int i = 0; i < 4; ++i)
        #pragma unroll
        for (int j = 0; j < 4; ++j)
          acc[i][j] += ar[i] * br[j];
    }
  }
  float4 bl = *(const float4*)(bias + n0 + tn * 4);
  float bb[4] = {bl.x, bl.y, bl.z, bl.w};
  #pragma unroll
  for (int i = 0; i < 4; ++i) {
    float4 v;
    v.x = acc[i][0] + bb[0]; v.y = acc[i][1] + bb[1];
    v.z = acc[i][2] + bb[2]; v.w = acc[i][3] + bb[3];
    *(float4*)(C + (size_t)(m0 + tm * 4 + i) * H_ + n0 + tn * 4) = v;
  }
}

// small naive GEMM for decoder init (M=32): C = concat(A1,A2)@W^T + bias
__global__ __launch_bounds__(256) void gemm_cat_small_k(
    const float* __restrict__ A1, const float* __restrict__ A2,
    const float* __restrict__ W, const float* __restrict__ bias,
    float* __restrict__ C, int M, int N, int K)
{
  const int tid   = threadIdx.x;
  const int col   = tid & 31;
  const int rg    = tid >> 5;
  const int n     = blockIdx.y * 32 + col;
  const int K1 = K >> 1;
  float acc[4] = {0, 0, 0, 0};
  const float4* __restrict__ w4 = (const float4*)(W + (size_t)n * K);
  for (int pass = 0; pass < 2; ++pass) {
    const float* __restrict__ A = pass ? A2 : A1;
    const float4* __restrict__ wp = w4 + pass * (K1 >> 2);
    for (int k = 0; k < (K1 >> 2); ++k) {
      float4 w = wp[k];
      #pragma unroll
      for (int i = 0; i < 4; ++i) {
        int rr = rg + (i << 3);
        if (rr < M) acc[i] += dot4(w, ((const float4*)(A + (size_t)rr * K1))[k]);
      }
    }
  }
  const float bv = bias[n];
  #pragma unroll
  for (int i = 0; i < 4; ++i) {
    int rr = rg + (i << 3);
    if (rr < M) C[(size_t)rr * N + n] = acc[i] + bv;
  }
}

// logits[b, t, s] = bvt + sum_h vt[h] * tanh(pre1[s,b,h] + Q[t,b,h])
#define ACH 256
__global__ __launch_bounds__(256) void attn_k(
    const float* __restrict__ pre1, const float* __restrict__ Qm,
    const float* __restrict__ vt, const float* __restrict__ bvt,
    float* __restrict__ out)
{
  __shared__ float sp[16][ACH + 4];
  __shared__ float sq[16][ACH + 4];
  __shared__ float sv[ACH];
  const int b     = blockIdx.z;
  const int tbase = blockIdx.y << 4;
  const int sbase = blockIdx.x << 4;
  const int tid   = threadIdx.x;
  const int so    = tid & 15;
  const int to    = tid >> 4;
  float acc = 0.f;

  for (int h0 = 0; h0 < H_; h0 += ACH) {
    __syncthreads();
    #pragma unroll
    for (int u = 0; u < (16 * ACH) / 256; ++u) {
      int idx = tid + u * 256;
      int i = idx >> 8;
      int h = idx & (ACH - 1);
      sq[i][h] = Qm[((size_t)(tbase + i) * B_ + b) * H_ + h0 + h];
      sp[i][h] = pre1[((size_t)(sbase + i) * B_ + b) * H_ + h0 + h];
    }
    if (tid < ACH) sv[tid] = vt[h0 + tid];
    __syncthreads();
    #pragma unroll 4
    for (int h = 0; h < ACH; ++h)
      acc += sv[h] * tanh_fast(sp[so][h] + sq[to][h]);
  }
  out[((size_t)b * S_ + tbase + to) * S_ + sbase + so] = acc + bvt[0];
}

extern "C" void kernel_launch(void* const* d_in, const int* in_sizes, int n_in,
                              void* d_out, int out_size, void* d_ws, size_t ws_size,
                              hipStream_t stream)
{
  (void)in_sizes; (void)n_in; (void)out_size; (void)ws_size;
  const float* x     = (const float*)d_in[0];
  const float* WihF  = (const float*)d_in[1];
  const float* WhhF  = (const float*)d_in[2];
  const float* bF    = (const float*)d_in[3];
  const float* WihR  = (const float*)d_in[4];
  const float* WhhR  = (const float*)d_in[5];
  const float* bR    = (const float*)d_in[6];
  /* d_in[7] = Wih_d unused by reference decoder */
  const float* WhhD  = (const float*)d_in[8];
  const float* bD    = (const float*)d_in[9];
  const float* Wr_h  = (const float*)d_in[10];
  const float* br_h  = (const float*)d_in[11];
  const float* Wr_c  = (const float*)d_in[12];
  const float* br_c  = (const float*)d_in[13];
  const float* W1    = (const float*)d_in[14];
  const float* b1    = (const float*)d_in[15];
  const float* W2    = (const float*)d_in[16];
  const float* b2    = (const float*)d_in[17];
  const float* vt    = (const float*)d_in[18];
  const float* bvt   = (const float*)d_in[19];
  float* out = (float*)d_out;
  float* ws  = (float*)d_ws;

  const size_t SBH = (size_t)S_ * B_ * H_;
  const size_t BH  = (size_t)B_ * H_;

  float* hs_f = ws;
  float* hs_r = ws + SBH;
  float* pre1 = ws + 2 * SBH;
  float* cF   = ws + 3 * SBH;
  float* cR   = cF + BH;
  float* cD   = cR + BH;
  float* hd0  = cD + BH;
  int*   bars = (int*)(ws + 3 * SBH + 4 * BH);
  float* hdec = hs_f;   // reuse after pre1
  float* Qm   = hs_r;   // reuse after pre1

  hipMemsetAsync(bars, 0, 1024, stream);

  // encoder: persistent, 4 groups x 64 blocks, 512 steps in-kernel
  enc_coop_k<<<256, 256, 0, stream>>>(x, WihF, WhhF, bF, WihR, WhhR, bR,
                                      cF, cR, hs_f, hs_r, bars);

  // decoder init (small)
  gemm_cat_small_k<<<dim3(1, 16), 256, 0, stream>>>(hs_f + (size_t)(S_ - 1) * BH, hs_r,
                                                    Wr_h, br_h, hd0, B_, H_, 2 * H_);
  gemm_cat_small_k<<<dim3(1, 16), 256, 0, stream>>>(cF, cR, Wr_c, br_c, cD, B_, H_, 2 * H_);

  // pre1 = (hs_f + hs_r) @ W1^T + b1   (tiled)
  gemm_tiled_k<1><<<dim3(256, 8), 256, 0, stream>>>(hs_f, hs_r, W1, b1, pre1);

  // decoder: persistent, 4 groups x 64 blocks
  dec_coop_k<<<256, 256, 0, stream>>>(hd0, cD, WhhD, bD, hdec, bars);

  // Q = Hdec @ W2^T + b2   (tiled)
  gemm_tiled_k<0><<<dim3(256, 8), 256, 0, stream>>>(hdec, nullptr, W2, b2, Qm);

  // attention
  attn_k<<<dim3(32, 32, 32), 256, 0, stream>>>(pre1, Qm, vt, bvt, out);
}

// Round 4
// 8269.051 us; speedup vs baseline: 5.9750x; 2.2498x over previous
//
#include <hip/hip_runtime.h>
#include <hip/hip_bf16.h>
#include <cstdint>
#include <cstddef>

#define B_ 32
#define S_ 512
#define D_ 256
#define H_ 512

typedef _Float16 h2 __attribute__((ext_vector_type(2)));
typedef _Float16 h4 __attribute__((ext_vector_type(4)));

__device__ __forceinline__ h2 H2(unsigned u) { return __builtin_bit_cast(h2, u); }
__device__ __forceinline__ unsigned U2(h2 v) { return __builtin_bit_cast(unsigned, v); }

#if __has_builtin(__builtin_amdgcn_fdot2)
__device__ __forceinline__ float dot2f(h2 a, h2 b, float c) {
  return __builtin_amdgcn_fdot2(a, b, c, false);
}
#else
__device__ __forceinline__ float dot2f(h2 a, h2 b, float c) {
  return c + (float)a.x * (float)b.x + (float)a.y * (float)b.y;
}
#endif

#if __has_builtin(__builtin_amdgcn_exp2f)
__device__ __forceinline__ float exp2_fast(float x) { return __builtin_amdgcn_exp2f(x); }
#else
__device__ __forceinline__ float exp2_fast(float x) { return exp2f(x); }
#endif
#if __has_builtin(__builtin_amdgcn_rcpf)
__device__ __forceinline__ float rcp_fast(float x) { return __builtin_amdgcn_rcpf(x); }
#else
__device__ __forceinline__ float rcp_fast(float x) { return 1.0f / x; }
#endif

__device__ __forceinline__ float sigm(float x) {
  return rcp_fast(1.0f + exp2_fast(-1.4426950408889634f * x));
}
__device__ __forceinline__ float tanh_fast(float x) {
  return 1.0f - 2.0f * rcp_fast(1.0f + exp2_fast(2.8853900817779268f * x));
}

// Coherent 16B load (bypass L1/L2, read L3): pipelined — caller batches the
// waitcnt. volatile asms stay ordered; the explicit waitcnt fences the uses.
__device__ __forceinline__ uint4 coh_load16(const void* p) {
  uint4 v;
  asm volatile("global_load_dwordx4 %0, %1, off sc0 sc1"
               : "=v"(v) : "v"(p) : "memory");
  return v;
}
__device__ __forceinline__ void vm_drain() {
  asm volatile("s_waitcnt vmcnt(0)" ::: "memory");
}

// Group barrier (64 blocks). Producer stores are sc0/sc1 write-through and
// drained via vm_drain before entry; relaxed add + relaxed spin suffice.
__device__ __forceinline__ void group_sync(int* bar, int target) {
  __syncthreads();
  if (threadIdx.x == 0) {
    __hip_atomic_fetch_add(bar, 1, __ATOMIC_RELAXED, __HIP_MEMORY_SCOPE_AGENT);
    while (__hip_atomic_load(bar, __ATOMIC_RELAXED, __HIP_MEMORY_SCOPE_AGENT) < target)
      __builtin_amdgcn_s_sleep(2);
  }
  __syncthreads();
}

// fp32 -> fp16 convert (4 elems/thread)
__global__ __launch_bounds__(256) void f2h_k(const float* __restrict__ src,
                                             _Float16* __restrict__ dst, int n4) {
  int i = blockIdx.x * 256 + threadIdx.x;
  if (i < n4) {
    float4 v = ((const float4*)src)[i];
    h4 o = {(_Float16)v.x, (_Float16)v.y, (_Float16)v.z, (_Float16)v.w};
    ((h4*)dst)[i] = o;
  }
}

// ---------------- persistent encoder ----------------
// 512 blocks = 8 groups (2 dir x 4 batch-quarters of 8) x 64 blocks.
// Block: 32 wrows (8 cols x 4 gates) fp16 in LDS; h exchange fp16 via L3.
__global__ __launch_bounds__(256, 2) void enc_coop_k(
    const _Float16* __restrict__ xh,
    const _Float16* __restrict__ WihF, const _Float16* __restrict__ WhhF, const float* __restrict__ bF,
    const _Float16* __restrict__ WihR, const _Float16* __restrict__ WhhR, const float* __restrict__ bR,
    float* __restrict__ cF, float* __restrict__ cR,
    _Float16* __restrict__ hsF, _Float16* __restrict__ hsR,
    int* __restrict__ bars)
{
  __shared__ __align__(16) _Float16 whh_l[32][520];  // +8 pad: 4-bank row shift
  __shared__ __align__(16) _Float16 wih_l[32][264];
  __shared__ __align__(16) _Float16 hbuf[8][520];
  __shared__ __align__(16) _Float16 xbuf[8][264];
  __shared__ float zbuf[32][9];
  __shared__ float cls[8][9];

  const int bid   = blockIdx.x;
  const int group = bid >> 6;          // 0..7
  const int dir   = group >> 2;
  const int bq    = group & 3;         // batches bq*8 .. +7
  const int jb    = bid & 63;
  const int c0    = jb << 3;
  const int tid   = threadIdx.x;

  const _Float16* __restrict__ Wih = dir ? WihR : WihF;
  const _Float16* __restrict__ Whh = dir ? WhhR : WhhF;
  const float* __restrict__ bias   = dir ? bR : bF;
  _Float16* __restrict__ hs   = dir ? hsR : hsF;
  float* __restrict__ cOut    = dir ? cR : cF;
  int* bar = bars + group * 32;

  for (int idx = tid; idx < 32 * 64; idx += 256) {
    int r = idx >> 6, j = idx & 63;
    int wrow = (r >> 3) * H_ + c0 + (r & 7);
    *(uint4*)&whh_l[r][j * 8] = *(const uint4*)(Whh + (size_t)wrow * H_ + j * 8);
  }
  for (int idx = tid; idx < 32 * 32; idx += 256) {
    int r = idx >> 5, j = idx & 31;
    int wrow = (r >> 3) * H_ + c0 + (r & 7);
    *(uint4*)&wih_l[r][j * 8] = *(const uint4*)(Wih + (size_t)wrow * D_ + j * 8);
  }

  const int r  = tid >> 3;             // wrow 0..31
  const int bs = tid & 7;              // batch within group
  const int wrow = (r >> 3) * H_ + c0 + (r & 7);
  const float bv = bias[wrow];
  __syncthreads();

  int target = 0;
  for (int t = 0; t < S_; ++t) {
    const int xi = dir ? (S_ - 1 - t) : t;

    {  // stage x row (8 batches x 512B) — normal cached loads
      int rb = tid >> 5, j = tid & 31;
      uint4 xv = *(const uint4*)(xh + ((size_t)(bq * 8 + rb) * S_ + xi) * D_ + j * 8);
      if (t > 0) {  // stage h (8 batches x 1KB) — pipelined coherent loads
        const int xip = dir ? xi + 1 : xi - 1;
        int hr = tid >> 5, j0 = (tid & 31) * 2;
        const _Float16* src = hs + ((size_t)xip * B_ + bq * 8 + hr) * H_ + j0 * 8;
        uint4 v0 = coh_load16(src);
        uint4 v1 = coh_load16(src + 8);
        vm_drain();
        *(uint4*)&hbuf[hr][j0 * 8]     = v0;
        *(uint4*)&hbuf[hr][j0 * 8 + 8] = v1;
      }
      *(uint4*)&xbuf[rb][j * 8] = xv;
    }
    __syncthreads();

    float za = 0.f, zc = 0.f;
    {
      const uint4* wi = (const uint4*)&wih_l[r][0];
      const uint4* xb = (const uint4*)&xbuf[bs][0];
      #pragma unroll 8
      for (int j = 0; j < 32; ++j) {
        uint4 w = wi[j], a = xb[j];
        za = dot2f(H2(w.x), H2(a.x), za);
        zc = dot2f(H2(w.y), H2(a.y), zc);
        za = dot2f(H2(w.z), H2(a.z), za);
        zc = dot2f(H2(w.w), H2(a.w), zc);
      }
    }
    if (t > 0) {
      const uint4* wr = (const uint4*)&whh_l[r][0];
      const uint4* hb = (const uint4*)&hbuf[bs][0];
      #pragma unroll 8
      for (int j = 0; j < 64; ++j) {
        uint4 w = wr[j], a = hb[j];
        za = dot2f(H2(w.x), H2(a.x), za);
        zc = dot2f(H2(w.y), H2(a.y), zc);
        za = dot2f(H2(w.z), H2(a.z), za);
        zc = dot2f(H2(w.w), H2(a.w), zc);
      }
    }
    zbuf[r][bs] = za + zc + bv;
    __syncthreads();

    if (tid < 64) {  // cell: 8 cols x 8 batches
      const int b = tid >> 3, cc = tid & 7;
      const float zi = zbuf[cc][b];
      const float zf = zbuf[8 + cc][b];
      const float zg = zbuf[16 + cc][b];
      const float zo = zbuf[24 + cc][b];
      const float c_old = (t == 0) ? 0.f : cls[cc][b];
      const float cn = sigm(zf) * c_old + sigm(zi) * tanh_fast(zg);
      const float hn = sigm(zo) * tanh_fast(cn);
      cls[cc][b] = cn;
      _Float16 hh = (_Float16)hn;
      __hip_atomic_store((unsigned short*)(hs + ((size_t)xi * B_ + bq * 8 + b) * H_ + c0 + cc),
                         __builtin_bit_cast(unsigned short, hh),
                         __ATOMIC_RELAXED, __HIP_MEMORY_SCOPE_AGENT);
      if (t == S_ - 1) cOut[(size_t)(bq * 8 + b) * H_ + c0 + cc] = cn;
    }

    if (t == S_ - 1) break;
    vm_drain();
    target += 64;
    group_sync(bar, target);
  }
}

// ---------------- persistent decoder ----------------
// 512 blocks = 8 groups (4 batches) x 64 blocks; 2 K-halves per (row,batch).
__global__ __launch_bounds__(256, 2) void dec_coop_k(
    const float* __restrict__ hd0, const float* __restrict__ cD0,
    const _Float16* __restrict__ Whh, const float* __restrict__ bias,
    _Float16* __restrict__ hdec, int* __restrict__ bars)
{
  __shared__ __align__(16) _Float16 whh_l[32][520];
  __shared__ __align__(16) _Float16 hbuf[4][520];
  __shared__ float zbuf[32][9];
  __shared__ float cls[8][5];

  const int bid   = blockIdx.x;
  const int group = bid >> 6;          // batches group*4 .. +3
  const int g4    = group * 4;
  const int jb    = bid & 63;
  const int c0    = jb << 3;
  const int tid   = threadIdx.x;
  int* bar = bars + (8 + group) * 32;

  for (int idx = tid; idx < 32 * 64; idx += 256) {
    int r = idx >> 6, j = idx & 63;
    int wrow = (r >> 3) * H_ + c0 + (r & 7);
    *(uint4*)&whh_l[r][j * 8] = *(const uint4*)(Whh + (size_t)wrow * H_ + j * 8);
  }
  if (tid < 32) {
    const int b = tid >> 3, cc = tid & 7;
    cls[cc][b] = cD0[(size_t)(g4 + b) * H_ + c0 + cc];
  }

  const int r  = tid >> 3;             // 0..31
  const int bs = (tid >> 1) & 3;       // batch 0..3
  const int kh = tid & 1;              // K half
  const int wrow = (r >> 3) * H_ + c0 + (r & 7);
  const float bv = bias[wrow];
  __syncthreads();

  int target = 0;
  for (int t = 0; t < S_; ++t) {
    {  // stage h_{t-1}: 4 batches x 1KB fp16
      int hr = tid >> 6, j = tid & 63;
      if (t == 0) {
        const float* src = hd0 + (size_t)(g4 + hr) * H_ + j * 8;
        float4 f0 = *(const float4*)src;
        float4 f1 = *(const float4*)(src + 4);
        h2 p0 = {(_Float16)f0.x, (_Float16)f0.y};
        h2 p1 = {(_Float16)f0.z, (_Float16)f0.w};
        h2 p2 = {(_Float16)f1.x, (_Float16)f1.y};
        h2 p3 = {(_Float16)f1.z, (_Float16)f1.w};
        uint4 v = {U2(p0), U2(p1), U2(p2), U2(p3)};
        *(uint4*)&hbuf[hr][j * 8] = v;
      } else {
        const _Float16* src = hdec + ((size_t)(t - 1) * B_ + g4 + hr) * H_ + j * 8;
        uint4 v = coh_load16(src);
        vm_drain();
        *(uint4*)&hbuf[hr][j * 8] = v;
      }
    }
    __syncthreads();

    float za = 0.f, zc = 0.f;
    {
      const uint4* wr = (const uint4*)&whh_l[r][0] + kh * 32;
      const uint4* hb = (const uint4*)&hbuf[bs][0] + kh * 32;
      #pragma unroll 8
      for (int j = 0; j < 32; ++j) {
        uint4 w = wr[j], a = hb[j];
        za = dot2f(H2(w.x), H2(a.x), za);
        zc = dot2f(H2(w.y), H2(a.y), zc);
        za = dot2f(H2(w.z), H2(a.z), za);
        zc = dot2f(H2(w.w), H2(a.w), zc);
      }
    }
    zbuf[r][bs * 2 + kh] = za + zc + (kh ? 0.f : bv);
    __syncthreads();

    if (tid < 32) {  // cell: 8 cols x 4 batches
      const int b = tid >> 3, cc = tid & 7;
      const float zi = zbuf[cc][b * 2]      + zbuf[cc][b * 2 + 1];
      const float zf = zbuf[8 + cc][b * 2]  + zbuf[8 + cc][b * 2 + 1];
      const float zg = zbuf[16 + cc][b * 2] + zbuf[16 + cc][b * 2 + 1];
      const float zo = zbuf[24 + cc][b * 2] + zbuf[24 + cc][b * 2 + 1];
      const float cn = sigm(zf) * cls[cc][b] + sigm(zi) * tanh_fast(zg);
      const float hn = sigm(zo) * tanh_fast(cn);
      cls[cc][b] = cn;
      _Float16 hh = (_Float16)hn;
      __hip_atomic_store((unsigned short*)(hdec + ((size_t)t * B_ + g4 + b) * H_ + c0 + cc),
                         __builtin_bit_cast(unsigned short, hh),
                         __ATOMIC_RELAXED, __HIP_MEMORY_SCOPE_AGENT);
    }

    if (t == S_ - 1) break;
    vm_drain();
    target += 64;
    group_sync(bar, target);
  }
}

// ---------------- fp16 dot2 tiled GEMM: C[M,512] = op(A)@W^T + bias ----------
// MODE 0: A1 ; MODE 1: A1 + A2. A,W,C fp16; accumulate fp32. 64x64 tile.
template <int MODE>
__global__ __launch_bounds__(256) void gemm_h_k(
    const _Float16* __restrict__ A1, const _Float16* __restrict__ A2,
    const _Float16* __restrict__ W, const float* __restrict__ bias,
    _Float16* __restrict__ C)
{
  __shared__ h2 As2[16][68];
  __shared__ h2 Bs2[16][68];
  const int tid = threadIdx.x;
  const int m0 = blockIdx.x * 64, n0 = blockIdx.y * 64;
  const int tn = tid & 15, tm = tid >> 4;
  float acc[4][4] = {};

  for (int kc = 0; kc < H_; kc += 32) {
    __syncthreads();
    {
      int mm = tid >> 2, q = tid & 3;
      uint4 a = *(const uint4*)(A1 + (size_t)(m0 + mm) * H_ + kc + q * 8);
      if (MODE == 1) {
        uint4 a2 = *(const uint4*)(A2 + (size_t)(m0 + mm) * H_ + kc + q * 8);
        a.x = U2(H2(a.x) + H2(a2.x)); a.y = U2(H2(a.y) + H2(a2.y));
        a.z = U2(H2(a.z) + H2(a2.z)); a.w = U2(H2(a.w) + H2(a2.w));
      }
      As2[q * 4 + 0][mm] = H2(a.x); As2[q * 4 + 1][mm] = H2(a.y);
      As2[q * 4 + 2][mm] = H2(a.z); As2[q * 4 + 3][mm] = H2(a.w);
      uint4 b = *(const uint4*)(W + (size_t)(n0 + mm) * H_ + kc + q * 8);
      Bs2[q * 4 + 0][mm] = H2(b.x); Bs2[q * 4 + 1][mm] = H2(b.y);
      Bs2[q * 4 + 2][mm] = H2(b.z); Bs2[q * 4 + 3][mm] = H2(b.w);
    }
    __syncthreads();
    #pragma unroll
    for (int k2 = 0; k2 < 16; ++k2) {
      uint4 au = *(const uint4*)&As2[k2][tm * 4];
      uint4 bu = *(const uint4*)&Bs2[k2][tn * 4];
      h2 a[4] = {H2(au.x), H2(au.y), H2(au.z), H2(au.w)};
      h2 b[4] = {H2(bu.x), H2(bu.y), H2(bu.z), H2(bu.w)};
      #pragma unroll
      for (int i = 0; i < 4; ++i)
        #pragma unroll
        for (int j = 0; j < 4; ++j)
          acc[i][j] = dot2f(a[i], b[j], acc[i][j]);
    }
  }
  float4 bl = *(const float4*)(bias + n0 + tn * 4);
  #pragma unroll
  for (int i = 0; i < 4; ++i) {
    h2 p0 = {(_Float16)(acc[i][0] + bl.x), (_Float16)(acc[i][1] + bl.y)};
    h2 p1 = {(_Float16)(acc[i][2] + bl.z), (_Float16)(acc[i][3] + bl.w)};
    uint2 st = {U2(p0), U2(p1)};
    *(uint2*)(C + (size_t)(m0 + tm * 4 + i) * H_ + n0 + tn * 4) = st;
  }
}

__device__ __forceinline__ float4 load4f(const float* p) { return *(const float4*)p; }
__device__ __forceinline__ float4 load4f(const _Float16* p) {
  uint2 u = *(const uint2*)p;
  h2 a = H2(u.x), b = H2(u.y);
  return make_float4((float)a.x, (float)a.y, (float)b.x, (float)b.y);
}

// small: C[32,512] = concat(A1,A2)@W^T + bias (K = 1024, halves of 512)
template <typename T>
__global__ __launch_bounds__(256) void gemm_cat_small_k(
    const T* __restrict__ A1, const T* __restrict__ A2,
    const float* __restrict__ W, const float* __restrict__ bias,
    float* __restrict__ C)
{
  const int tid = threadIdx.x;
  const int col = tid & 31;
  const int rg  = tid >> 5;
  const int n   = blockIdx.y * 32 + col;
  float acc[4] = {0, 0, 0, 0};
  #pragma unroll
  for (int pass = 0; pass < 2; ++pass) {
    const T* __restrict__ A = pass ? A2 : A1;
    const float4* __restrict__ w4 = (const float4*)(W + (size_t)n * 1024 + pass * 512);
    for (int k4 = 0; k4 < 128; ++k4) {
      float4 w = w4[k4];
      #pragma unroll
      for (int i = 0; i < 4; ++i) {
        int row = rg + (i << 3);
        float4 a = load4f(A + (size_t)row * H_ + k4 * 4);
        acc[i] += w.x * a.x + w.y * a.y + w.z * a.z + w.w * a.w;
      }
    }
  }
  const float bv = bias[n];
  #pragma unroll
  for (int i = 0; i < 4; ++i) {
    int row = rg + (i << 3);
    C[(size_t)row * H_ + n] = acc[i] + bv;
  }
}

// logits[b, t, s] = bvt + sum_h vt[h] * tanh(pre1[s,b,h] + Q[t,b,h])
#define ACH 256
__global__ __launch_bounds__(256) void attn_k(
    const _Float16* __restrict__ pre1, const _Float16* __restrict__ Qm,
    const float* __restrict__ vt, const float* __restrict__ bvt,
    float* __restrict__ out)
{
  __shared__ float sp[16][ACH + 4];
  __shared__ float sq[16][ACH + 4];
  __shared__ float sv[ACH];
  const int b     = blockIdx.z;
  const int tbase = blockIdx.y << 4;
  const int sbase = blockIdx.x << 4;
  const int tid   = threadIdx.x;
  const int so    = tid & 15;
  const int to    = tid >> 4;
  float acc = 0.f;

  for (int h0 = 0; h0 < H_; h0 += ACH) {
    __syncthreads();
    {
      int i = tid >> 4, off = (tid & 15) * 16;
      uint4 q0 = *(const uint4*)(Qm + ((size_t)(tbase + i) * B_ + b) * H_ + h0 + off);
      uint4 q1 = *(const uint4*)(Qm + ((size_t)(tbase + i) * B_ + b) * H_ + h0 + off + 8);
      uint4 p0 = *(const uint4*)(pre1 + ((size_t)(sbase + i) * B_ + b) * H_ + h0 + off);
      uint4 p1 = *(const uint4*)(pre1 + ((size_t)(sbase + i) * B_ + b) * H_ + h0 + off + 8);
      const unsigned* qs = (const unsigned*)&q0;
      const unsigned* ps = (const unsigned*)&p0;
      #pragma unroll
      for (int u = 0; u < 4; ++u) {
        h2 qv = H2(qs[u]), pv = H2(ps[u]);
        sq[i][off + u * 2] = (float)qv.x; sq[i][off + u * 2 + 1] = (float)qv.y;
        sp[i][off + u * 2] = (float)pv.x; sp[i][off + u * 2 + 1] = (float)pv.y;
      }
      const unsigned* qs2 = (const unsigned*)&q1;
      const unsigned* ps2 = (const unsigned*)&p1;
      #pragma unroll
      for (int u = 0; u < 4; ++u) {
        h2 qv = H2(qs2[u]), pv = H2(ps2[u]);
        sq[i][off + 8 + u * 2] = (float)qv.x; sq[i][off + 8 + u * 2 + 1] = (float)qv.y;
        sp[i][off + 8 + u * 2] = (float)pv.x; sp[i][off + 8 + u * 2 + 1] = (float)pv.y;
      }
    }
    sv[tid] = vt[h0 + tid];
    __syncthreads();
    #pragma unroll 4
    for (int h = 0; h < ACH; ++h)
      acc += sv[h] * tanh_fast(sp[so][h] + sq[to][h]);
  }
  out[((size_t)b * S_ + tbase + to) * S_ + sbase + so] = acc + bvt[0];
}

extern "C" void kernel_launch(void* const* d_in, const int* in_sizes, int n_in,
                              void* d_out, int out_size, void* d_ws, size_t ws_size,
                              hipStream_t stream)
{
  (void)in_sizes; (void)n_in; (void)out_size; (void)ws_size;
  const float* x     = (const float*)d_in[0];
  const float* WihF  = (const float*)d_in[1];
  const float* WhhF  = (const float*)d_in[2];
  const float* bF    = (const float*)d_in[3];
  const float* WihR  = (const float*)d_in[4];
  const float* WhhR  = (const float*)d_in[5];
  const float* bR    = (const float*)d_in[6];
  /* d_in[7] = Wih_d unused by reference decoder */
  const float* WhhD  = (const float*)d_in[8];
  const float* bD    = (const float*)d_in[9];
  const float* Wr_h  = (const float*)d_in[10];
  const float* br_h  = (const float*)d_in[11];
  const float* Wr_c  = (const float*)d_in[12];
  const float* br_c  = (const float*)d_in[13];
  const float* W1    = (const float*)d_in[14];
  const float* b1    = (const float*)d_in[15];
  const float* W2    = (const float*)d_in[16];
  const float* b2    = (const float*)d_in[17];
  const float* vt    = (const float*)d_in[18];
  const float* bvt   = (const float*)d_in[19];
  float* out = (float*)d_out;

  const size_t SBH = (size_t)S_ * B_ * H_;   // 8,388,608
  const size_t BH  = (size_t)B_ * H_;

  _Float16* hp = (_Float16*)d_ws;
  _Float16* hs_f  = hp;              hp += SBH;
  _Float16* hs_r  = hp;              hp += SBH;
  _Float16* pre1h = hp;              hp += SBH;
  _Float16* Qmh   = hp;              hp += SBH;
  _Float16* xh    = hp;              hp += (size_t)B_ * S_ * D_;
  _Float16* wihF  = hp;              hp += (size_t)4 * H_ * D_;
  _Float16* wihR  = hp;              hp += (size_t)4 * H_ * D_;
  _Float16* whhF  = hp;              hp += (size_t)4 * H_ * H_;
  _Float16* whhR  = hp;              hp += (size_t)4 * H_ * H_;
  _Float16* whhD  = hp;              hp += (size_t)4 * H_ * H_;
  _Float16* w1h   = hp;              hp += (size_t)H_ * H_;
  _Float16* w2h   = hp;              hp += (size_t)H_ * H_;
  float* fp  = (float*)hp;
  float* cF  = fp;                   fp += BH;
  float* cR  = fp;                   fp += BH;
  float* cD  = fp;                   fp += BH;
  float* hd0 = fp;                   fp += BH;
  int*   bars = (int*)fp;
  _Float16* hdec = hs_f;             // alias: dead after pre1/hd0

  hipMemsetAsync(bars, 0, 4096, stream);

  // fp32 -> fp16 converts
  f2h_k<<<(B_ * S_ * D_ / 4 + 255) / 256, 256, 0, stream>>>(x, xh, B_ * S_ * D_ / 4);
  f2h_k<<<(4 * H_ * D_ / 4 + 255) / 256, 256, 0, stream>>>(WihF, wihF, 4 * H_ * D_ / 4);
  f2h_k<<<(4 * H_ * D_ / 4 + 255) / 256, 256, 0, stream>>>(WihR, wihR, 4 * H_ * D_ / 4);
  f2h_k<<<(4 * H_ * H_ / 4 + 255) / 256, 256, 0, stream>>>(WhhF, whhF, 4 * H_ * H_ / 4);
  f2h_k<<<(4 * H_ * H_ / 4 + 255) / 256, 256, 0, stream>>>(WhhR, whhR, 4 * H_ * H_ / 4);
  f2h_k<<<(4 * H_ * H_ / 4 + 255) / 256, 256, 0, stream>>>(WhhD, whhD, 4 * H_ * H_ / 4);
  f2h_k<<<(H_ * H_ / 4 + 255) / 256, 256, 0, stream>>>(W1, w1h, H_ * H_ / 4);
  f2h_k<<<(H_ * H_ / 4 + 255) / 256, 256, 0, stream>>>(W2, w2h, H_ * H_ / 4);

  // encoder: persistent, 8 groups x 64 blocks
  enc_coop_k<<<512, 256, 0, stream>>>(xh, wihF, whhF, bF, wihR, whhR, bR,
                                      cF, cR, hs_f, hs_r, bars);

  // decoder init
  gemm_cat_small_k<_Float16><<<dim3(1, 16), 256, 0, stream>>>(
      hs_f + (size_t)(S_ - 1) * BH, hs_r, Wr_h, br_h, hd0);
  gemm_cat_small_k<float><<<dim3(1, 16), 256, 0, stream>>>(cF, cR, Wr_c, br_c, cD);

  // pre1 = (hs_f + hs_r) @ W1^T + b1
  gemm_h_k<1><<<dim3(256, 8), 256, 0, stream>>>(hs_f, hs_r, w1h, b1, pre1h);

  // decoder: persistent, 8 groups x 64 blocks
  dec_coop_k<<<512, 256, 0, stream>>>(hd0, cD, whhD, bD, hdec, bars);

  // Q = Hdec @ W2^T + b2
  gemm_h_k<0><<<dim3(256, 8), 256, 0, stream>>>(hdec, nullptr, w2h, b2, Qmh);

  // attention
  attn_k<<<dim3(32, 32, 32), 256, 0, stream>>>(pre1h, Qmh, vt, bvt, out);
}

// Round 8
// 7173.155 us; speedup vs baseline: 6.8879x; 1.1528x over previous
//
#include <hip/hip_runtime.h>
#include <hip/hip_bf16.h>
#include <cstdint>
#include <cstddef>

#define B_ 32
#define S_ 512
#define D_ 256
#define H_ 512

typedef _Float16 h2 __attribute__((ext_vector_type(2)));
typedef _Float16 h4 __attribute__((ext_vector_type(4)));
typedef _Float16 h8 __attribute__((ext_vector_type(8)));
typedef float f32x4 __attribute__((ext_vector_type(4)));

__device__ __forceinline__ h2 H2(unsigned u) { return __builtin_bit_cast(h2, u); }
__device__ __forceinline__ unsigned U2(h2 v) { return __builtin_bit_cast(unsigned, v); }

#if __has_builtin(__builtin_amdgcn_fdot2)
__device__ __forceinline__ float dot2f(h2 a, h2 b, float c) {
  return __builtin_amdgcn_fdot2(a, b, c, false);
}
#else
__device__ __forceinline__ float dot2f(h2 a, h2 b, float c) {
  return c + (float)a.x * (float)b.x + (float)a.y * (float)b.y;
}
#endif

#if __has_builtin(__builtin_amdgcn_exp2f)
__device__ __forceinline__ float exp2_fast(float x) { return __builtin_amdgcn_exp2f(x); }
#else
__device__ __forceinline__ float exp2_fast(float x) { return exp2f(x); }
#endif
#if __has_builtin(__builtin_amdgcn_rcpf)
__device__ __forceinline__ float rcp_fast(float x) { return __builtin_amdgcn_rcpf(x); }
#else
__device__ __forceinline__ float rcp_fast(float x) { return 1.0f / x; }
#endif

__device__ __forceinline__ float sigm(float x) {
  return rcp_fast(1.0f + exp2_fast(-1.4426950408889634f * x));
}
__device__ __forceinline__ float tanh_fast(float x) {
  return 1.0f - 2.0f * rcp_fast(1.0f + exp2_fast(2.8853900817779268f * x));
}

// Coherent 16B load (bypass L1/L2, read L3). Caller MUST vm_drain() before use.
__device__ __forceinline__ uint4 coh_load16(const void* p) {
  uint4 v;
  asm volatile("global_load_dwordx4 %0, %1, off sc0 sc1"
               : "=v"(v) : "v"(p) : "memory");
  return v;
}
__device__ __forceinline__ void vm_drain() {
  asm volatile("s_waitcnt vmcnt(0)" ::: "memory");
}

// Group barrier. h-stores are sc0/sc1 write-through and drained via vm_drain
// before entry; relaxed add + relaxed spin suffice (no L2 inv/wb).
__device__ __forceinline__ void group_sync(int* bar, int target) {
  __syncthreads();
  if (threadIdx.x == 0) {
    __hip_atomic_fetch_add(bar, 1, __ATOMIC_RELAXED, __HIP_MEMORY_SCOPE_AGENT);
    while (__hip_atomic_load(bar, __ATOMIC_RELAXED, __HIP_MEMORY_SCOPE_AGENT) < target)
      __builtin_amdgcn_s_sleep(2);
  }
  __syncthreads();
}

// fp32 -> fp16 convert (4 elems/thread)
__global__ __launch_bounds__(256) void f2h_k(const float* __restrict__ src,
                                             _Float16* __restrict__ dst, int n4) {
  int i = blockIdx.x * 256 + threadIdx.x;
  if (i < n4) {
    float4 v = ((const float4*)src)[i];
    h4 o = {(_Float16)v.x, (_Float16)v.y, (_Float16)v.z, (_Float16)v.w};
    ((h4*)dst)[i] = o;
  }
}

// ---------------- persistent encoder: MFMA compute, r4-IDENTICAL sync -------
// 512 blocks = 8 groups (dir x 4 batch-quarters of 8) x 64 blocks.
// Block: 8 h-cols x 4 gates; wave = gate. MFMA 16x16x32 with rows 8..15 zero
// (A zero-padded) and B cols 8..15 unused. Weights live in VGPRs (aw[24]).
// Exchange protocol (8-batch groups, 64-block barrier, atomic-short h stores,
// coh_load16 h staging) is byte-equivalent to the round-4 PASSING kernel.
__global__ __launch_bounds__(256, 1) void enc_coop_k(
    const _Float16* __restrict__ xh,
    const _Float16* __restrict__ WihF, const _Float16* __restrict__ WhhF, const float* __restrict__ bF,
    const _Float16* __restrict__ WihR, const _Float16* __restrict__ WhhR, const float* __restrict__ bR,
    float* __restrict__ cF, float* __restrict__ cR,
    _Float16* __restrict__ hsF, _Float16* __restrict__ hsR,
    int* __restrict__ bars)
{
  __shared__ __align__(16) _Float16 cbuf[96][16][8];  // [k8][n][8]; n>=8 dead
  __shared__ float zfin[4][8][9];                     // [gate][col][batch]
  __shared__ float cls[8][9];                         // c-state [col][batch]

  const int bid = blockIdx.x;
  const int group = bid >> 6;       // 0..7 = dir*4 + quarter
  const int dir = group >> 2;
  const int q8 = (group & 3) << 3;  // batch base (8 batches per group)
  const int jb = bid & 63;
  const int c0 = jb << 3;           // 8 h-cols per block
  const int tid = threadIdx.x;
  const int lane = tid & 63;
  const int wv = tid >> 6;          // wave = gate 0..3

  const _Float16* __restrict__ Wih = dir ? WihR : WihF;
  const _Float16* __restrict__ Whh = dir ? WhhR : WhhF;
  const float* __restrict__ bias = dir ? bR : bF;
  _Float16* __restrict__ hs = dir ? hsR : hsF;
  float* __restrict__ cOut = dir ? cR : cF;
  int* bar = bars + group * 32;

  // zero cbuf once (hygiene for the unused n>=8 columns)
  for (int i = tid; i < 1536; i += 256) {
    uint4 z = {0, 0, 0, 0};
    ((uint4*)cbuf)[i] = z;
  }

  // A-fragments: lane holds W'[row = c0 + (lane&15), gate wv][k-octet lane>>4]
  // rows 8..15 are zero padding.
  h8 aw[24];
  {
    const int m = lane & 15, kg = lane >> 4;
    const h8 zz = {0, 0, 0, 0, 0, 0, 0, 0};
    const int wrow = wv * H_ + c0 + (m & 7);
    const _Float16* wi = Wih + (size_t)wrow * D_;
    const _Float16* wh = Whh + (size_t)wrow * H_;
    #pragma unroll
    for (int tu = 0; tu < 24; ++tu) {
      int k = tu * 32 + kg * 8;
      h8 w = (k < 256) ? *(const h8*)(wi + k) : *(const h8*)(wh + (k - 256));
      aw[tu] = (m < 8) ? w : zz;
    }
  }

  // cell identity (tid<64 active in cell): col cc, batch cb
  const int cc = tid & 7, cb = tid >> 3;
  float bvg[4];
  #pragma unroll
  for (int g = 0; g < 4; ++g) bvg[g] = bias[g * H_ + c0 + cc];

  const char* cbase = (const char*)cbuf + (size_t)((lane >> 4) * 256 + (lane & 15) * 16);
  const int sn = tid & 7, k8b = (tid >> 3) * 3;   // staging: batch sn, 3 octets
  __syncthreads();

  int target = 0;
  for (int t = 0; t < S_; ++t) {
    const int xi = dir ? (S_ - 1 - t) : t;
    {  // ---- stage [x ; h_{t-1}] -> cbuf: x normal loads, h coherent loads
      const int xip = dir ? (xi + 1 < S_ ? xi + 1 : xi) : (xi > 0 ? xi - 1 : 0);
      uint4 vs[3];
      #pragma unroll
      for (int u = 0; u < 3; ++u) {
        const int k8 = k8b + u;
        if (k8 < 32)
          vs[u] = *(const uint4*)(xh + ((size_t)(q8 + sn) * S_ + xi) * D_ + k8 * 8);
        else
          vs[u] = coh_load16(hs + ((size_t)xip * B_ + q8 + sn) * H_ + (k8 - 32) * 8);
      }
      vm_drain();
      #pragma unroll
      for (int u = 0; u < 3; ++u) {
        const int k8 = k8b + u;
        uint4 v = vs[u];
        if (t == 0 && k8 >= 32) { v.x = 0; v.y = 0; v.z = 0; v.w = 0; }
        *(uint4*)&cbuf[k8][sn][0] = v;
      }
    }
    __syncthreads();

    f32x4 acc = {0.f, 0.f, 0.f, 0.f};
    #pragma unroll
    for (int tu = 0; tu < 24; ++tu) {
      h8 bf = *(const h8*)(cbase + tu * 1024);
      acc = __builtin_amdgcn_mfma_f32_16x16x32_f16(aw[tu], bf, acc, 0, 0, 0);
    }
    {  // D: col(lane&15)=batch, row=(lane>>4)*4+r = block col; keep <8 only
      const int mrow = (lane >> 4) * 4, n = lane & 15;
      if (mrow < 8 && n < 8) {
        #pragma unroll
        for (int r = 0; r < 4; ++r) zfin[wv][mrow + r][n] = acc[r];
      }
    }
    __syncthreads();

    if (tid < 64) {  // cell: 8 cols x 8 batches
      const float zi = zfin[0][cc][cb] + bvg[0];
      const float zf = zfin[1][cc][cb] + bvg[1];
      const float zg = zfin[2][cc][cb] + bvg[2];
      const float zo = zfin[3][cc][cb] + bvg[3];
      const float c_old = (t == 0) ? 0.f : cls[cc][cb];
      const float cn = sigm(zf) * c_old + sigm(zi) * tanh_fast(zg);
      const float hn = sigm(zo) * tanh_fast(cn);
      cls[cc][cb] = cn;
      _Float16 hh = (_Float16)hn;
      __hip_atomic_store((unsigned short*)(hs + ((size_t)xi * B_ + q8 + cb) * H_ + c0 + cc),
                         __builtin_bit_cast(unsigned short, hh),
                         __ATOMIC_RELAXED, __HIP_MEMORY_SCOPE_AGENT);
      if (t == S_ - 1) cOut[(size_t)(q8 + cb) * H_ + c0 + cc] = cn;
    }
    if (t == S_ - 1) break;
    vm_drain();
    target += 64;
    group_sync(bar, target);
  }
}

// ---------------- persistent decoder (round-4 dot2 text, KNOWN GOOD) --------
// 512 blocks = 8 groups (4 batches) x 64 blocks; 2 K-halves per (row,batch).
__global__ __launch_bounds__(256, 2) void dec_coop_k(
    const float* __restrict__ hd0, const float* __restrict__ cD0,
    const _Float16* __restrict__ Whh, const float* __restrict__ bias,
    _Float16* __restrict__ hdec, int* __restrict__ bars)
{
  __shared__ __align__(16) _Float16 whh_l[32][520];
  __shared__ __align__(16) _Float16 hbuf[4][520];
  __shared__ float zbuf[32][9];
  __shared__ float cls[8][5];

  const int bid   = blockIdx.x;
  const int group = bid >> 6;          // batches group*4 .. +3
  const int g4    = group * 4;
  const int jb    = bid & 63;
  const int c0    = jb << 3;
  const int tid   = threadIdx.x;
  int* bar = bars + (8 + group) * 32;

  for (int idx = tid; idx < 32 * 64; idx += 256) {
    int r = idx >> 6, j = idx & 63;
    int wrow = (r >> 3) * H_ + c0 + (r & 7);
    *(uint4*)&whh_l[r][j * 8] = *(const uint4*)(Whh + (size_t)wrow * H_ + j * 8);
  }
  if (tid < 32) {
    const int b = tid >> 3, cc = tid & 7;
    cls[cc][b] = cD0[(size_t)(g4 + b) * H_ + c0 + cc];
  }

  const int r  = tid >> 3;             // 0..31
  const int bs = (tid >> 1) & 3;       // batch 0..3
  const int kh = tid & 1;              // K half
  const int wrow = (r >> 3) * H_ + c0 + (r & 7);
  const float bv = bias[wrow];
  __syncthreads();

  int target = 0;
  for (int t = 0; t < S_; ++t) {
    {  // stage h_{t-1}: 4 batches x 1KB fp16
      int hr = tid >> 6, j = tid & 63;
      if (t == 0) {
        const float* src = hd0 + (size_t)(g4 + hr) * H_ + j * 8;
        float4 f0 = *(const float4*)src;
        float4 f1 = *(const float4*)(src + 4);
        h2 p0 = {(_Float16)f0.x, (_Float16)f0.y};
        h2 p1 = {(_Float16)f0.z, (_Float16)f0.w};
        h2 p2 = {(_Float16)f1.x, (_Float16)f1.y};
        h2 p3 = {(_Float16)f1.z, (_Float16)f1.w};
        uint4 v = {U2(p0), U2(p1), U2(p2), U2(p3)};
        *(uint4*)&hbuf[hr][j * 8] = v;
      } else {
        const _Float16* src = hdec + ((size_t)(t - 1) * B_ + g4 + hr) * H_ + j * 8;
        uint4 v = coh_load16(src);
        vm_drain();
        *(uint4*)&hbuf[hr][j * 8] = v;
      }
    }
    __syncthreads();

    float za = 0.f, zc = 0.f;
    {
      const uint4* wr = (const uint4*)&whh_l[r][0] + kh * 32;
      const uint4* hb = (const uint4*)&hbuf[bs][0] + kh * 32;
      #pragma unroll 8
      for (int j = 0; j < 32; ++j) {
        uint4 w = wr[j], a = hb[j];
        za = dot2f(H2(w.x), H2(a.x), za);
        zc = dot2f(H2(w.y), H2(a.y), zc);
        za = dot2f(H2(w.z), H2(a.z), za);
        zc = dot2f(H2(w.w), H2(a.w), zc);
      }
    }
    zbuf[r][bs * 2 + kh] = za + zc + (kh ? 0.f : bv);
    __syncthreads();

    if (tid < 32) {  // cell: 8 cols x 4 batches
      const int b = tid >> 3, cc = tid & 7;
      const float zi = zbuf[cc][b * 2]      + zbuf[cc][b * 2 + 1];
      const float zf = zbuf[8 + cc][b * 2]  + zbuf[8 + cc][b * 2 + 1];
      const float zg = zbuf[16 + cc][b * 2] + zbuf[16 + cc][b * 2 + 1];
      const float zo = zbuf[24 + cc][b * 2] + zbuf[24 + cc][b * 2 + 1];
      const float cn = sigm(zf) * cls[cc][b] + sigm(zi) * tanh_fast(zg);
      const float hn = sigm(zo) * tanh_fast(cn);
      cls[cc][b] = cn;
      _Float16 hh = (_Float16)hn;
      __hip_atomic_store((unsigned short*)(hdec + ((size_t)t * B_ + g4 + b) * H_ + c0 + cc),
                         __builtin_bit_cast(unsigned short, hh),
                         __ATOMIC_RELAXED, __HIP_MEMORY_SCOPE_AGENT);
    }

    if (t == S_ - 1) break;
    vm_drain();
    target += 64;
    group_sync(bar, target);
  }
}

// ---------------- fp16 dot2 tiled GEMM: C[M,512] = op(A)@W^T + bias ----------
template <int MODE>
__global__ __launch_bounds__(256) void gemm_h_k(
    const _Float16* __restrict__ A1, const _Float16* __restrict__ A2,
    const _Float16* __restrict__ W, const float* __restrict__ bias,
    _Float16* __restrict__ C)
{
  __shared__ h2 As2[16][68];
  __shared__ h2 Bs2[16][68];
  const int tid = threadIdx.x;
  const int m0 = blockIdx.x * 64, n0 = blockIdx.y * 64;
  const int tn = tid & 15, tm = tid >> 4;
  float acc[4][4] = {};

  for (int kc = 0; kc < H_; kc += 32) {
    __syncthreads();
    {
      int mm = tid >> 2, q = tid & 3;
      uint4 a = *(const uint4*)(A1 + (size_t)(m0 + mm) * H_ + kc + q * 8);
      if (MODE == 1) {
        uint4 a2 = *(const uint4*)(A2 + (size_t)(m0 + mm) * H_ + kc + q * 8);
        a.x = U2(H2(a.x) + H2(a2.x)); a.y = U2(H2(a.y) + H2(a2.y));
        a.z = U2(H2(a.z) + H2(a2.z)); a.w = U2(H2(a.w) + H2(a2.w));
      }
      As2[q * 4 + 0][mm] = H2(a.x); As2[q * 4 + 1][mm] = H2(a.y);
      As2[q * 4 + 2][mm] = H2(a.z); As2[q * 4 + 3][mm] = H2(a.w);
      uint4 b = *(const uint4*)(W + (size_t)(n0 + mm) * H_ + kc + q * 8);
      Bs2[q * 4 + 0][mm] = H2(b.x); Bs2[q * 4 + 1][mm] = H2(b.y);
      Bs2[q * 4 + 2][mm] = H2(b.z); Bs2[q * 4 + 3][mm] = H2(b.w);
    }
    __syncthreads();
    #pragma unroll
    for (int k2 = 0; k2 < 16; ++k2) {
      uint4 au = *(const uint4*)&As2[k2][tm * 4];
      uint4 bu = *(const uint4*)&Bs2[k2][tn * 4];
      h2 a[4] = {H2(au.x), H2(au.y), H2(au.z), H2(au.w)};
      h2 b[4] = {H2(bu.x), H2(bu.y), H2(bu.z), H2(bu.w)};
      #pragma unroll
      for (int i = 0; i < 4; ++i)
        #pragma unroll
        for (int j = 0; j < 4; ++j)
          acc[i][j] = dot2f(a[i], b[j], acc[i][j]);
    }
  }
  float4 bl = *(const float4*)(bias + n0 + tn * 4);
  #pragma unroll
  for (int i = 0; i < 4; ++i) {
    h2 p0 = {(_Float16)(acc[i][0] + bl.x), (_Float16)(acc[i][1] + bl.y)};
    h2 p1 = {(_Float16)(acc[i][2] + bl.z), (_Float16)(acc[i][3] + bl.w)};
    uint2 st = {U2(p0), U2(p1)};
    *(uint2*)(C + (size_t)(m0 + tm * 4 + i) * H_ + n0 + tn * 4) = st;
  }
}

__device__ __forceinline__ float4 load4f(const float* p) { return *(const float4*)p; }
__device__ __forceinline__ float4 load4f(const _Float16* p) {
  uint2 u = *(const uint2*)p;
  h2 a = H2(u.x), b = H2(u.y);
  return make_float4((float)a.x, (float)a.y, (float)b.x, (float)b.y);
}

// small: C[32,512] = concat(A1,A2)@W^T + bias (K = 1024, halves of 512)
template <typename T>
__global__ __launch_bounds__(256) void gemm_cat_small_k(
    const T* __restrict__ A1, const T* __restrict__ A2,
    const float* __restrict__ W, const float* __restrict__ bias,
    float* __restrict__ C)
{
  const int tid = threadIdx.x;
  const int col = tid & 31;
  const int rg  = tid >> 5;
  const int n   = blockIdx.y * 32 + col;
  float acc[4] = {0, 0, 0, 0};
  #pragma unroll
  for (int pass = 0; pass < 2; ++pass) {
    const T* __restrict__ A = pass ? A2 : A1;
    const float4* __restrict__ w4 = (const float4*)(W + (size_t)n * 1024 + pass * 512);
    for (int k4 = 0; k4 < 128; ++k4) {
      float4 w = w4[k4];
      #pragma unroll
      for (int i = 0; i < 4; ++i) {
        int row = rg + (i << 3);
        float4 a = load4f(A + (size_t)row * H_ + k4 * 4);
        acc[i] += w.x * a.x + w.y * a.y + w.z * a.z + w.w * a.w;
      }
    }
  }
  const float bv = bias[n];
  #pragma unroll
  for (int i = 0; i < 4; ++i) {
    int row = rg + (i << 3);
    C[(size_t)row * H_ + n] = acc[i] + bv;
  }
}

// logits[b, t, s] = bvt + sum_h vt[h] * tanh(pre1[s,b,h] + Q[t,b,h])
// (round-4 text, KNOWN GOOD)
__global__ __launch_bounds__(256) void attn_k(
    const _Float16* __restrict__ pre1, const _Float16* __restrict__ Qm,
    const float* __restrict__ vt, const float* __restrict__ bvt,
    float* __restrict__ out)
{
  __shared__ float sp[16][260];
  __shared__ float sq[16][260];
  __shared__ float sv[256];
  const int b = blockIdx.z, tbase = blockIdx.y << 4, sbase = blockIdx.x << 4;
  const int tid = threadIdx.x;
  const int so = tid & 15;
  const int to = tid >> 4;
  float acc = 0.f;

  for (int h0 = 0; h0 < H_; h0 += 256) {
    __syncthreads();
    {
      int i = tid >> 4, off = (tid & 15) * 16;
      uint4 q0 = *(const uint4*)(Qm + ((size_t)(tbase + i) * B_ + b) * H_ + h0 + off);
      uint4 q1 = *(const uint4*)(Qm + ((size_t)(tbase + i) * B_ + b) * H_ + h0 + off + 8);
      uint4 p0 = *(const uint4*)(pre1 + ((size_t)(sbase + i) * B_ + b) * H_ + h0 + off);
      uint4 p1 = *(const uint4*)(pre1 + ((size_t)(sbase + i) * B_ + b) * H_ + h0 + off + 8);
      const unsigned* qs = (const unsigned*)&q0;
      const unsigned* ps = (const unsigned*)&p0;
      #pragma unroll
      for (int u = 0; u < 4; ++u) {
        h2 qv = H2(qs[u]), pv = H2(ps[u]);
        sq[i][off + u * 2] = (float)qv.x; sq[i][off + u * 2 + 1] = (float)qv.y;
        sp[i][off + u * 2] = (float)pv.x; sp[i][off + u * 2 + 1] = (float)pv.y;
      }
      const unsigned* qs2 = (const unsigned*)&q1;
      const unsigned* ps2 = (const unsigned*)&p1;
      #pragma unroll
      for (int u = 0; u < 4; ++u) {
        h2 qv = H2(qs2[u]), pv = H2(ps2[u]);
        sq[i][off + 8 + u * 2] = (float)qv.x; sq[i][off + 8 + u * 2 + 1] = (float)qv.y;
        sp[i][off + 8 + u * 2] = (float)pv.x; sp[i][off + 8 + u * 2 + 1] = (float)pv.y;
      }
    }
    sv[tid] = vt[h0 + tid];
    __syncthreads();
    #pragma unroll 4
    for (int h = 0; h < 256; ++h)
      acc += sv[h] * tanh_fast(sp[so][h] + sq[to][h]);
  }
  out[((size_t)b * S_ + tbase + to) * S_ + sbase + so] = acc + bvt[0];
}

extern "C" void kernel_launch(void* const* d_in, const int* in_sizes, int n_in,
                              void* d_out, int out_size, void* d_ws, size_t ws_size,
                              hipStream_t stream)
{
  (void)in_sizes; (void)n_in; (void)out_size; (void)ws_size;
  const float* x     = (const float*)d_in[0];
  const float* WihF  = (const float*)d_in[1];
  const float* WhhF  = (const float*)d_in[2];
  const float* bF    = (const float*)d_in[3];
  const float* WihR  = (const float*)d_in[4];
  const float* WhhR  = (const float*)d_in[5];
  const float* bR    = (const float*)d_in[6];
  /* d_in[7] = Wih_d unused by reference decoder */
  const float* WhhD  = (const float*)d_in[8];
  const float* bD    = (const float*)d_in[9];
  const float* Wr_h  = (const float*)d_in[10];
  const float* br_h  = (const float*)d_in[11];
  const float* Wr_c  = (const float*)d_in[12];
  const float* br_c  = (const float*)d_in[13];
  const float* W1    = (const float*)d_in[14];
  const float* b1    = (const float*)d_in[15];
  const float* W2    = (const float*)d_in[16];
  const float* b2    = (const float*)d_in[17];
  const float* vt    = (const float*)d_in[18];
  const float* bvt   = (const float*)d_in[19];
  float* out = (float*)d_out;

  const size_t SBH = (size_t)S_ * B_ * H_;   // 8,388,608
  const size_t BH  = (size_t)B_ * H_;

  _Float16* hp = (_Float16*)d_ws;
  _Float16* hs_f  = hp;              hp += SBH;
  _Float16* hs_r  = hp;              hp += SBH;
  _Float16* pre1h = hp;              hp += SBH;
  _Float16* Qmh   = hp;              hp += SBH;
  _Float16* xh    = hp;              hp += (size_t)B_ * S_ * D_;
  _Float16* wihF  = hp;              hp += (size_t)4 * H_ * D_;
  _Float16* wihR  = hp;              hp += (size_t)4 * H_ * D_;
  _Float16* whhF  = hp;              hp += (size_t)4 * H_ * H_;
  _Float16* whhR  = hp;              hp += (size_t)4 * H_ * H_;
  _Float16* whhD  = hp;              hp += (size_t)4 * H_ * H_;
  _Float16* w1h   = hp;              hp += (size_t)H_ * H_;
  _Float16* w2h   = hp;              hp += (size_t)H_ * H_;
  float* fp  = (float*)hp;
  float* cF  = fp;                   fp += BH;
  float* cR  = fp;                   fp += BH;
  float* cD  = fp;                   fp += BH;
  float* hd0 = fp;                   fp += BH;
  int*   bars = (int*)fp;
  _Float16* hdec = hs_f;             // alias: dead after pre1/hd0

  hipMemsetAsync(bars, 0, 4096, stream);

  // fp32 -> fp16 converts
  f2h_k<<<(B_ * S_ * D_ / 4 + 255) / 256, 256, 0, stream>>>(x, xh, B_ * S_ * D_ / 4);
  f2h_k<<<(4 * H_ * D_ / 4 + 255) / 256, 256, 0, stream>>>(WihF, wihF, 4 * H_ * D_ / 4);
  f2h_k<<<(4 * H_ * D_ / 4 + 255) / 256, 256, 0, stream>>>(WihR, wihR, 4 * H_ * D_ / 4);
  f2h_k<<<(4 * H_ * H_ / 4 + 255) / 256, 256, 0, stream>>>(WhhF, whhF, 4 * H_ * H_ / 4);
  f2h_k<<<(4 * H_ * H_ / 4 + 255) / 256, 256, 0, stream>>>(WhhR, whhR, 4 * H_ * H_ / 4);
  f2h_k<<<(4 * H_ * H_ / 4 + 255) / 256, 256, 0, stream>>>(WhhD, whhD, 4 * H_ * H_ / 4);
  f2h_k<<<(H_ * H_ / 4 + 255) / 256, 256, 0, stream>>>(W1, w1h, H_ * H_ / 4);
  f2h_k<<<(H_ * H_ / 4 + 255) / 256, 256, 0, stream>>>(W2, w2h, H_ * H_ / 4);

  // encoder: persistent MFMA with r4-identical sync, 8 groups x 64 blocks
  enc_coop_k<<<512, 256, 0, stream>>>(xh, wihF, whhF, bF, wihR, whhR, bR,
                                      cF, cR, hs_f, hs_r, bars);

  // decoder init
  gemm_cat_small_k<_Float16><<<dim3(1, 16), 256, 0, stream>>>(
      hs_f + (size_t)(S_ - 1) * BH, hs_r, Wr_h, br_h, hd0);
  gemm_cat_small_k<float><<<dim3(1, 16), 256, 0, stream>>>(cF, cR, Wr_c, br_c, cD);

  // pre1 = (hs_f + hs_r) @ W1^T + b1
  gemm_h_k<1><<<dim3(256, 8), 256, 0, stream>>>(hs_f, hs_r, w1h, b1, pre1h);

  // decoder: persistent dot2 (round-4, known good), 8 groups x 64 blocks
  dec_coop_k<<<512, 256, 0, stream>>>(hd0, cD, whhD, bD, hdec, bars);

  // Q = Hdec @ W2^T + b2
  gemm_h_k<0><<<dim3(256, 8), 256, 0, stream>>>(hdec, nullptr, w2h, b2, Qmh);

  // attention (round-4, known good)
  attn_k<<<dim3(32, 32, 32), 256, 0, stream>>>(pre1h, Qmh, vt, bvt, out);
}

// Round 9
// 6393.288 us; speedup vs baseline: 7.7281x; 1.1220x over previous
//
#include <hip/hip_runtime.h>
#include <hip/hip_bf16.h>
#include <cstdint>
#include <cstddef>

#define B_ 32
#define S_ 512
#define D_ 256
#define H_ 512

typedef _Float16 h2 __attribute__((ext_vector_type(2)));
typedef _Float16 h4 __attribute__((ext_vector_type(4)));
typedef _Float16 h8 __attribute__((ext_vector_type(8)));
typedef float f32x4 __attribute__((ext_vector_type(4)));

__device__ __forceinline__ h2 H2(unsigned u) { return __builtin_bit_cast(h2, u); }
__device__ __forceinline__ unsigned U2(h2 v) { return __builtin_bit_cast(unsigned, v); }

#if __has_builtin(__builtin_amdgcn_fdot2)
__device__ __forceinline__ float dot2f(h2 a, h2 b, float c) {
  return __builtin_amdgcn_fdot2(a, b, c, false);
}
#else
__device__ __forceinline__ float dot2f(h2 a, h2 b, float c) {
  return c + (float)a.x * (float)b.x + (float)a.y * (float)b.y;
}
#endif

#if __has_builtin(__builtin_amdgcn_exp2f)
__device__ __forceinline__ float exp2_fast(float x) { return __builtin_amdgcn_exp2f(x); }
#else
__device__ __forceinline__ float exp2_fast(float x) { return exp2f(x); }
#endif
#if __has_builtin(__builtin_amdgcn_rcpf)
__device__ __forceinline__ float rcp_fast(float x) { return __builtin_amdgcn_rcpf(x); }
#else
__device__ __forceinline__ float rcp_fast(float x) { return 1.0f / x; }
#endif

__device__ __forceinline__ float sigm(float x) {
  return rcp_fast(1.0f + exp2_fast(-1.4426950408889634f * x));
}
__device__ __forceinline__ float tanh_fast(float x) {
  return 1.0f - 2.0f * rcp_fast(1.0f + exp2_fast(2.8853900817779268f * x));
}

// Coherent 16B load (bypass L1/L2, read L3). Caller MUST vm_drain() before use.
__device__ __forceinline__ uint4 coh_load16(const void* p) {
  uint4 v;
  asm volatile("global_load_dwordx4 %0, %1, off sc0 sc1"
               : "=v"(v) : "v"(p) : "memory");
  return v;
}
__device__ __forceinline__ void vm_drain() {
  asm volatile("s_waitcnt vmcnt(0)" ::: "memory");
}

// Distributed flag barrier for a 64-block group. Each block stores the step
// epoch to its own flag (no atomic RMW contention); wave 0 vector-polls all
// 64 flags. Monotonic epochs -> no reset race. h-stores are sc0/sc1
// write-through and drained (vm_drain) before entry.
__device__ __forceinline__ void group_sync_flags(int* flags, int my, int t1) {
  __syncthreads();
  if (threadIdx.x < 64) {
    if (threadIdx.x == 0)
      __hip_atomic_store(flags + my, t1, __ATOMIC_RELAXED, __HIP_MEMORY_SCOPE_AGENT);
    for (;;) {
      int v = __hip_atomic_load(flags + (int)threadIdx.x,
                                __ATOMIC_RELAXED, __HIP_MEMORY_SCOPE_AGENT);
      if (__all(v >= t1)) break;
      __builtin_amdgcn_s_sleep(1);
    }
  }
  __syncthreads();
}

// fp32 -> fp16 convert (4 elems/thread)
__global__ __launch_bounds__(256) void f2h_k(const float* __restrict__ src,
                                             _Float16* __restrict__ dst, int n4) {
  int i = blockIdx.x * 256 + threadIdx.x;
  if (i < n4) {
    float4 v = ((const float4*)src)[i];
    h4 o = {(_Float16)v.x, (_Float16)v.y, (_Float16)v.z, (_Float16)v.w};
    ((h4*)dst)[i] = o;
  }
}

// ---------------- persistent encoder: MFMA, r8-PROVEN geometry --------------
// 512 blocks = 8 groups (dir x 4 batch-quarters of 8) x 64 blocks.
// Block: 8 h-cols x 4 gates; wave = gate. MFMA 16x16x32, A rows 8..15 zero.
// Only change vs passing r8: flag barrier instead of central counter.
__global__ __launch_bounds__(256, 1) void enc_coop_k(
    const _Float16* __restrict__ xh,
    const _Float16* __restrict__ WihF, const _Float16* __restrict__ WhhF, const float* __restrict__ bF,
    const _Float16* __restrict__ WihR, const _Float16* __restrict__ WhhR, const float* __restrict__ bR,
    float* __restrict__ cF, float* __restrict__ cR,
    _Float16* __restrict__ hsF, _Float16* __restrict__ hsR,
    int* __restrict__ bars)
{
  __shared__ __align__(16) _Float16 cbuf[96][16][8];  // [k8][n][8]; n>=8 dead
  __shared__ float zfin[4][8][9];                     // [gate][col][batch]
  __shared__ float cls[8][9];                         // c-state [col][batch]

  const int bid = blockIdx.x;
  const int group = bid >> 6;       // 0..7 = dir*4 + quarter
  const int dir = group >> 2;
  const int q8 = (group & 3) << 3;  // batch base (8 batches per group)
  const int jb = bid & 63;
  const int c0 = jb << 3;           // 8 h-cols per block
  const int tid = threadIdx.x;
  const int lane = tid & 63;
  const int wv = tid >> 6;          // wave = gate 0..3

  const _Float16* __restrict__ Wih = dir ? WihR : WihF;
  const _Float16* __restrict__ Whh = dir ? WhhR : WhhF;
  const float* __restrict__ bias = dir ? bR : bF;
  _Float16* __restrict__ hs = dir ? hsR : hsF;
  float* __restrict__ cOut = dir ? cR : cF;
  int* flg = bars + group * 64;

  // zero cbuf once (unused n>=8 columns stay zero)
  for (int i = tid; i < 1536; i += 256) {
    uint4 z = {0, 0, 0, 0};
    ((uint4*)cbuf)[i] = z;
  }

  // A-fragments: lane holds W'[row = c0 + (lane&15), gate wv][k-octet lane>>4]
  // rows 8..15 are zero padding.
  h8 aw[24];
  {
    const int m = lane & 15, kg = lane >> 4;
    const h8 zz = {0, 0, 0, 0, 0, 0, 0, 0};
    const int wrow = wv * H_ + c0 + (m & 7);
    const _Float16* wi = Wih + (size_t)wrow * D_;
    const _Float16* wh = Whh + (size_t)wrow * H_;
    #pragma unroll
    for (int tu = 0; tu < 24; ++tu) {
      int k = tu * 32 + kg * 8;
      h8 w = (k < 256) ? *(const h8*)(wi + k) : *(const h8*)(wh + (k - 256));
      aw[tu] = (m < 8) ? w : zz;
    }
  }

  const int cc = tid & 7, cb = tid >> 3;  // cell identity (tid<64)
  float bvg[4];
  #pragma unroll
  for (int g = 0; g < 4; ++g) bvg[g] = bias[g * H_ + c0 + cc];

  const char* cbase = (const char*)cbuf + (size_t)((lane >> 4) * 256 + (lane & 15) * 16);
  const int sn = tid & 7, k8b = (tid >> 3) * 3;   // staging: batch sn, 3 octets
  __syncthreads();

  for (int t = 0; t < S_; ++t) {
    const int xi = dir ? (S_ - 1 - t) : t;
    {  // ---- stage [x ; h_{t-1}] -> cbuf: x normal loads, h coherent loads
      const int xip = dir ? (xi + 1 < S_ ? xi + 1 : xi) : (xi > 0 ? xi - 1 : 0);
      uint4 vs[3];
      #pragma unroll
      for (int u = 0; u < 3; ++u) {
        const int k8 = k8b + u;
        if (k8 < 32)
          vs[u] = *(const uint4*)(xh + ((size_t)(q8 + sn) * S_ + xi) * D_ + k8 * 8);
        else
          vs[u] = coh_load16(hs + ((size_t)xip * B_ + q8 + sn) * H_ + (k8 - 32) * 8);
      }
      vm_drain();
      #pragma unroll
      for (int u = 0; u < 3; ++u) {
        const int k8 = k8b + u;
        uint4 v = vs[u];
        if (t == 0 && k8 >= 32) { v.x = 0; v.y = 0; v.z = 0; v.w = 0; }
        *(uint4*)&cbuf[k8][sn][0] = v;
      }
    }
    __syncthreads();

    f32x4 acc = {0.f, 0.f, 0.f, 0.f};
    #pragma unroll
    for (int tu = 0; tu < 24; ++tu) {
      h8 bf = *(const h8*)(cbase + tu * 1024);
      acc = __builtin_amdgcn_mfma_f32_16x16x32_f16(aw[tu], bf, acc, 0, 0, 0);
    }
    {  // D: col(lane&15)=batch, row=(lane>>4)*4+r = block col; keep <8 only
      const int mrow = (lane >> 4) * 4, n = lane & 15;
      if (mrow < 8 && n < 8) {
        #pragma unroll
        for (int r = 0; r < 4; ++r) zfin[wv][mrow + r][n] = acc[r];
      }
    }
    __syncthreads();

    if (tid < 64) {  // cell: 8 cols x 8 batches
      const float zi = zfin[0][cc][cb] + bvg[0];
      const float zf = zfin[1][cc][cb] + bvg[1];
      const float zg = zfin[2][cc][cb] + bvg[2];
      const float zo = zfin[3][cc][cb] + bvg[3];
      const float c_old = (t == 0) ? 0.f : cls[cc][cb];
      const float cn = sigm(zf) * c_old + sigm(zi) * tanh_fast(zg);
      const float hn = sigm(zo) * tanh_fast(cn);
      cls[cc][cb] = cn;
      _Float16 hh = (_Float16)hn;
      __hip_atomic_store((unsigned short*)(hs + ((size_t)xi * B_ + q8 + cb) * H_ + c0 + cc),
                         __builtin_bit_cast(unsigned short, hh),
                         __ATOMIC_RELAXED, __HIP_MEMORY_SCOPE_AGENT);
      if (t == S_ - 1) cOut[(size_t)(q8 + cb) * H_ + c0 + cc] = cn;
    }
    if (t == S_ - 1) break;
    vm_drain();
    group_sync_flags(flg, jb, t + 1);
  }
}

// ---------------- persistent decoder: MFMA, r4-PROVEN geometry --------------
// 512 blocks = 8 groups (4 batches) x 64 blocks; block: 8 h-cols x 4 gates.
// Same group/exchange geometry as the passing r4/r8 decoder; compute is MFMA
// (16 K-tiles, A rows 8..15 zero, B cols 4..15 zero).
__global__ __launch_bounds__(256, 1) void dec_coop_k(
    const float* __restrict__ hd0, const float* __restrict__ cD0,
    const _Float16* __restrict__ Whh, const float* __restrict__ bias,
    _Float16* __restrict__ hdec, int* __restrict__ bars)
{
  __shared__ __align__(16) _Float16 cbuf[64][16][8];  // [k8][n][8]; n>=4 dead
  __shared__ float zfin[4][8][5];
  __shared__ float cls[8][5];

  const int bid = blockIdx.x;
  const int group = bid >> 6;       // 0..7: batches group*4 .. +3
  const int g4 = group << 2;
  const int jb = bid & 63;
  const int c0 = jb << 3;
  const int tid = threadIdx.x;
  const int lane = tid & 63;
  const int wv = tid >> 6;
  int* flg = bars + (8 + group) * 64;

  for (int i = tid; i < 1024; i += 256) {
    uint4 z = {0, 0, 0, 0};
    ((uint4*)cbuf)[i] = z;
  }

  h8 aw[16];
  {
    const int m = lane & 15, kg = lane >> 4;
    const h8 zz = {0, 0, 0, 0, 0, 0, 0, 0};
    const _Float16* wh = Whh + (size_t)(wv * H_ + c0 + (m & 7)) * H_;
    #pragma unroll
    for (int tu = 0; tu < 16; ++tu) {
      h8 w = *(const h8*)(wh + tu * 32 + kg * 8);
      aw[tu] = (m < 8) ? w : zz;
    }
  }

  const int cc = tid & 7, cb = tid >> 3;  // cell identity (tid<32)
  float bvg[4];
  #pragma unroll
  for (int g = 0; g < 4; ++g) bvg[g] = bias[g * H_ + c0 + cc];
  if (tid < 32) cls[cc][cb] = cD0[(size_t)(g4 + cb) * H_ + c0 + cc];

  const char* cbase = (const char*)cbuf + (size_t)((lane >> 4) * 256 + (lane & 15) * 16);
  const int sn = tid & 3, k8 = tid >> 2;  // staging: batch sn, octet k8 (0..63)
  __syncthreads();

  for (int t = 0; t < S_; ++t) {
    {  // stage h_{t-1}: 4 batches x 64 octets, one uint4 per thread
      if (t == 0) {
        const float* src = hd0 + (size_t)(g4 + sn) * H_ + k8 * 8;
        float4 f0 = *(const float4*)src;
        float4 f1 = *(const float4*)(src + 4);
        h8 o = {(_Float16)f0.x, (_Float16)f0.y, (_Float16)f0.z, (_Float16)f0.w,
                (_Float16)f1.x, (_Float16)f1.y, (_Float16)f1.z, (_Float16)f1.w};
        *(h8*)&cbuf[k8][sn][0] = o;
      } else {
        uint4 v = coh_load16(hdec + ((size_t)(t - 1) * B_ + g4 + sn) * H_ + k8 * 8);
        vm_drain();
        *(uint4*)&cbuf[k8][sn][0] = v;
      }
    }
    __syncthreads();

    f32x4 acc = {0.f, 0.f, 0.f, 0.f};
    #pragma unroll
    for (int tu = 0; tu < 16; ++tu) {
      h8 bf = *(const h8*)(cbase + tu * 1024);
      acc = __builtin_amdgcn_mfma_f32_16x16x32_f16(aw[tu], bf, acc, 0, 0, 0);
    }
    {
      const int mrow = (lane >> 4) * 4, n = lane & 15;
      if (mrow < 8 && n < 4) {
        #pragma unroll
        for (int r = 0; r < 4; ++r) zfin[wv][mrow + r][n] = acc[r];
      }
    }
    __syncthreads();

    if (tid < 32) {  // cell: 8 cols x 4 batches
      const float zi = zfin[0][cc][cb] + bvg[0];
      const float zf = zfin[1][cc][cb] + bvg[1];
      const float zg = zfin[2][cc][cb] + bvg[2];
      const float zo = zfin[3][cc][cb] + bvg[3];
      const float cn = sigm(zf) * cls[cc][cb] + sigm(zi) * tanh_fast(zg);
      const float hn = sigm(zo) * tanh_fast(cn);
      cls[cc][cb] = cn;
      _Float16 hh = (_Float16)hn;
      __hip_atomic_store((unsigned short*)(hdec + ((size_t)t * B_ + g4 + cb) * H_ + c0 + cc),
                         __builtin_bit_cast(unsigned short, hh),
                         __ATOMIC_RELAXED, __HIP_MEMORY_SCOPE_AGENT);
    }
    if (t == S_ - 1) break;
    vm_drain();
    group_sync_flags(flg, jb, t + 1);
  }
}

// ---------------- fp16 dot2 tiled GEMM: C[M,512] = op(A)@W^T + bias ----------
template <int MODE>
__global__ __launch_bounds__(256) void gemm_h_k(
    const _Float16* __restrict__ A1, const _Float16* __restrict__ A2,
    const _Float16* __restrict__ W, const float* __restrict__ bias,
    _Float16* __restrict__ C)
{
  __shared__ h2 As2[16][68];
  __shared__ h2 Bs2[16][68];
  const int tid = threadIdx.x;
  const int m0 = blockIdx.x * 64, n0 = blockIdx.y * 64;
  const int tn = tid & 15, tm = tid >> 4;
  float acc[4][4] = {};

  for (int kc = 0; kc < H_; kc += 32) {
    __syncthreads();
    {
      int mm = tid >> 2, q = tid & 3;
      uint4 a = *(const uint4*)(A1 + (size_t)(m0 + mm) * H_ + kc + q * 8);
      if (MODE == 1) {
        uint4 a2 = *(const uint4*)(A2 + (size_t)(m0 + mm) * H_ + kc + q * 8);
        a.x = U2(H2(a.x) + H2(a2.x)); a.y = U2(H2(a.y) + H2(a2.y));
        a.z = U2(H2(a.z) + H2(a2.z)); a.w = U2(H2(a.w) + H2(a2.w));
      }
      As2[q * 4 + 0][mm] = H2(a.x); As2[q * 4 + 1][mm] = H2(a.y);
      As2[q * 4 + 2][mm] = H2(a.z); As2[q * 4 + 3][mm] = H2(a.w);
      uint4 b = *(const uint4*)(W + (size_t)(n0 + mm) * H_ + kc + q * 8);
      Bs2[q * 4 + 0][mm] = H2(b.x); Bs2[q * 4 + 1][mm] = H2(b.y);
      Bs2[q * 4 + 2][mm] = H2(b.z); Bs2[q * 4 + 3][mm] = H2(b.w);
    }
    __syncthreads();
    #pragma unroll
    for (int k2 = 0; k2 < 16; ++k2) {
      uint4 au = *(const uint4*)&As2[k2][tm * 4];
      uint4 bu = *(const uint4*)&Bs2[k2][tn * 4];
      h2 a[4] = {H2(au.x), H2(au.y), H2(au.z), H2(au.w)};
      h2 b[4] = {H2(bu.x), H2(bu.y), H2(bu.z), H2(bu.w)};
      #pragma unroll
      for (int i = 0; i < 4; ++i)
        #pragma unroll
        for (int j = 0; j < 4; ++j)
          acc[i][j] = dot2f(a[i], b[j], acc[i][j]);
    }
  }
  float4 bl = *(const float4*)(bias + n0 + tn * 4);
  #pragma unroll
  for (int i = 0; i < 4; ++i) {
    h2 p0 = {(_Float16)(acc[i][0] + bl.x), (_Float16)(acc[i][1] + bl.y)};
    h2 p1 = {(_Float16)(acc[i][2] + bl.z), (_Float16)(acc[i][3] + bl.w)};
    uint2 st = {U2(p0), U2(p1)};
    *(uint2*)(C + (size_t)(m0 + tm * 4 + i) * H_ + n0 + tn * 4) = st;
  }
}

__device__ __forceinline__ float4 load4f(const float* p) { return *(const float4*)p; }
__device__ __forceinline__ float4 load4f(const _Float16* p) {
  uint2 u = *(const uint2*)p;
  h2 a = H2(u.x), b = H2(u.y);
  return make_float4((float)a.x, (float)a.y, (float)b.x, (float)b.y);
}

// small: C[32,512] = concat(A1,A2)@W^T + bias (K = 1024, halves of 512)
template <typename T>
__global__ __launch_bounds__(256) void gemm_cat_small_k(
    const T* __restrict__ A1, const T* __restrict__ A2,
    const float* __restrict__ W, const float* __restrict__ bias,
    float* __restrict__ C)
{
  const int tid = threadIdx.x;
  const int col = tid & 31;
  const int rg  = tid >> 5;
  const int n   = blockIdx.y * 32 + col;
  float acc[4] = {0, 0, 0, 0};
  #pragma unroll
  for (int pass = 0; pass < 2; ++pass) {
    const T* __restrict__ A = pass ? A2 : A1;
    const float4* __restrict__ w4 = (const float4*)(W + (size_t)n * 1024 + pass * 512);
    for (int k4 = 0; k4 < 128; ++k4) {
      float4 w = w4[k4];
      #pragma unroll
      for (int i = 0; i < 4; ++i) {
        int row = rg + (i << 3);
        float4 a = load4f(A + (size_t)row * H_ + k4 * 4);
        acc[i] += w.x * a.x + w.y * a.y + w.z * a.z + w.w * a.w;
      }
    }
  }
  const float bv = bias[n];
  #pragma unroll
  for (int i = 0; i < 4; ++i) {
    int row = rg + (i << 3);
    C[(size_t)row * H_ + n] = acc[i] + bv;
  }
}

// logits[b, t, s] = bvt + sum_h vt[h] * tanh(pre1[s,b,h] + Q[t,b,h])
__global__ __launch_bounds__(256) void attn_k(
    const _Float16* __restrict__ pre1, const _Float16* __restrict__ Qm,
    const float* __restrict__ vt, const float* __restrict__ bvt,
    float* __restrict__ out)
{
  __shared__ float sp[16][260];
  __shared__ float sq[16][260];
  __shared__ float sv[256];
  const int b = blockIdx.z, tbase = blockIdx.y << 4, sbase = blockIdx.x << 4;
  const int tid = threadIdx.x;
  const int so = tid & 15;
  const int to = tid >> 4;
  float acc = 0.f;

  for (int h0 = 0; h0 < H_; h0 += 256) {
    __syncthreads();
    {
      int i = tid >> 4, off = (tid & 15) * 16;
      uint4 q0 = *(const uint4*)(Qm + ((size_t)(tbase + i) * B_ + b) * H_ + h0 + off);
      uint4 q1 = *(const uint4*)(Qm + ((size_t)(tbase + i) * B_ + b) * H_ + h0 + off + 8);
      uint4 p0 = *(const uint4*)(pre1 + ((size_t)(sbase + i) * B_ + b) * H_ + h0 + off);
      uint4 p1 = *(const uint4*)(pre1 + ((size_t)(sbase + i) * B_ + b) * H_ + h0 + off + 8);
      const unsigned* qs = (const unsigned*)&q0;
      const unsigned* ps = (const unsigned*)&p0;
      #pragma unroll
      for (int u = 0; u < 4; ++u) {
        h2 qv = H2(qs[u]), pv = H2(ps[u]);
        sq[i][off + u * 2] = (float)qv.x; sq[i][off + u * 2 + 1] = (float)qv.y;
        sp[i][off + u * 2] = (float)pv.x; sp[i][off + u * 2 + 1] = (float)pv.y;
      }
      const unsigned* qs2 = (const unsigned*)&q1;
      const unsigned* ps2 = (const unsigned*)&p1;
      #pragma unroll
      for (int u = 0; u < 4; ++u) {
        h2 qv = H2(qs2[u]), pv = H2(ps2[u]);
        sq[i][off + 8 + u * 2] = (float)qv.x; sq[i][off + 8 + u * 2 + 1] = (float)qv.y;
        sp[i][off + 8 + u * 2] = (float)pv.x; sp[i][off + 8 + u * 2 + 1] = (float)pv.y;
      }
    }
    sv[tid] = vt[h0 + tid];
    __syncthreads();
    #pragma unroll 4
    for (int h = 0; h < 256; ++h)
      acc += sv[h] * tanh_fast(sp[so][h] + sq[to][h]);
  }
  out[((size_t)b * S_ + tbase + to) * S_ + sbase + so] = acc + bvt[0];
}

extern "C" void kernel_launch(void* const* d_in, const int* in_sizes, int n_in,
                              void* d_out, int out_size, void* d_ws, size_t ws_size,
                              hipStream_t stream)
{
  (void)in_sizes; (void)n_in; (void)out_size; (void)ws_size;
  const float* x     = (const float*)d_in[0];
  const float* WihF  = (const float*)d_in[1];
  const float* WhhF  = (const float*)d_in[2];
  const float* bF    = (const float*)d_in[3];
  const float* WihR  = (const float*)d_in[4];
  const float* WhhR  = (const float*)d_in[5];
  const float* bR    = (const float*)d_in[6];
  /* d_in[7] = Wih_d unused by reference decoder */
  const float* WhhD  = (const float*)d_in[8];
  const float* bD    = (const float*)d_in[9];
  const float* Wr_h  = (const float*)d_in[10];
  const float* br_h  = (const float*)d_in[11];
  const float* Wr_c  = (const float*)d_in[12];
  const float* br_c  = (const float*)d_in[13];
  const float* W1    = (const float*)d_in[14];
  const float* b1    = (const float*)d_in[15];
  const float* W2    = (const float*)d_in[16];
  const float* b2    = (const float*)d_in[17];
  const float* vt    = (const float*)d_in[18];
  const float* bvt   = (const float*)d_in[19];
  float* out = (float*)d_out;

  const size_t SBH = (size_t)S_ * B_ * H_;   // 8,388,608
  const size_t BH  = (size_t)B_ * H_;

  _Float16* hp = (_Float16*)d_ws;
  _Float16* hs_f  = hp;              hp += SBH;
  _Float16* hs_r  = hp;              hp += SBH;
  _Float16* pre1h = hp;              hp += SBH;
  _Float16* Qmh   = hp;              hp += SBH;
  _Float16* xh    = hp;              hp += (size_t)B_ * S_ * D_;
  _Float16* wihF  = hp;              hp += (size_t)4 * H_ * D_;
  _Float16* wihR  = hp;              hp += (size_t)4 * H_ * D_;
  _Float16* whhF  = hp;              hp += (size_t)4 * H_ * H_;
  _Float16* whhR  = hp;              hp += (size_t)4 * H_ * H_;
  _Float16* whhD  = hp;              hp += (size_t)4 * H_ * H_;
  _Float16* w1h   = hp;              hp += (size_t)H_ * H_;
  _Float16* w2h   = hp;              hp += (size_t)H_ * H_;
  float* fp  = (float*)hp;
  float* cF  = fp;                   fp += BH;
  float* cR  = fp;                   fp += BH;
  float* cD  = fp;                   fp += BH;
  float* hd0 = fp;                   fp += BH;
  int*   bars = (int*)fp;
  _Float16* hdec = hs_f;             // alias: dead after pre1/hd0

  hipMemsetAsync(bars, 0, 8192, stream);

  // fp32 -> fp16 converts
  f2h_k<<<(B_ * S_ * D_ / 4 + 255) / 256, 256, 0, stream>>>(x, xh, B_ * S_ * D_ / 4);
  f2h_k<<<(4 * H_ * D_ / 4 + 255) / 256, 256, 0, stream>>>(WihF, wihF, 4 * H_ * D_ / 4);
  f2h_k<<<(4 * H_ * D_ / 4 + 255) / 256, 256, 0, stream>>>(WihR, wihR, 4 * H_ * D_ / 4);
  f2h_k<<<(4 * H_ * H_ / 4 + 255) / 256, 256, 0, stream>>>(WhhF, whhF, 4 * H_ * H_ / 4);
  f2h_k<<<(4 * H_ * H_ / 4 + 255) / 256, 256, 0, stream>>>(WhhR, whhR, 4 * H_ * H_ / 4);
  f2h_k<<<(4 * H_ * H_ / 4 + 255) / 256, 256, 0, stream>>>(WhhD, whhD, 4 * H_ * H_ / 4);
  f2h_k<<<(H_ * H_ / 4 + 255) / 256, 256, 0, stream>>>(W1, w1h, H_ * H_ / 4);
  f2h_k<<<(H_ * H_ / 4 + 255) / 256, 256, 0, stream>>>(W2, w2h, H_ * H_ / 4);

  // encoder: persistent MFMA + flag barrier, 8 groups x 64 blocks
  enc_coop_k<<<512, 256, 0, stream>>>(xh, wihF, whhF, bF, wihR, whhR, bR,
                                      cF, cR, hs_f, hs_r, bars);

  // decoder init
  gemm_cat_small_k<_Float16><<<dim3(1, 16), 256, 0, stream>>>(
      hs_f + (size_t)(S_ - 1) * BH, hs_r, Wr_h, br_h, hd0);
  gemm_cat_small_k<float><<<dim3(1, 16), 256, 0, stream>>>(cF, cR, Wr_c, br_c, cD);

  // pre1 = (hs_f + hs_r) @ W1^T + b1
  gemm_h_k<1><<<dim3(256, 8), 256, 0, stream>>>(hs_f, hs_r, w1h, b1, pre1h);

  // decoder: persistent MFMA + flag barrier, 8 groups x 64 blocks
  dec_coop_k<<<512, 256, 0, stream>>>(hd0, cD, whhD, bD, hdec, bars);

  // Q = Hdec @ W2^T + b2
  gemm_h_k<0><<<dim3(256, 8), 256, 0, stream>>>(hdec, nullptr, w2h, b2, Qmh);

  // attention
  attn_k<<<dim3(32, 32, 32), 256, 0, stream>>>(pre1h, Qmh, vt, bvt, out);
}

// Round 11
// 5746.482 us; speedup vs baseline: 8.5980x; 1.1126x over previous
//
#include <hip/hip_runtime.h>
#include <hip/hip_bf16.h>
#include <cstdint>
#include <cstddef>

#define B_ 32
#define S_ 512
#define D_ 256
#define H_ 512

typedef _Float16 h2 __attribute__((ext_vector_type(2)));
typedef _Float16 h4 __attribute__((ext_vector_type(4)));
typedef _Float16 h8 __attribute__((ext_vector_type(8)));
typedef float f32x4 __attribute__((ext_vector_type(4)));

__device__ __forceinline__ h2 H2(unsigned u) { return __builtin_bit_cast(h2, u); }
__device__ __forceinline__ unsigned U2(h2 v) { return __builtin_bit_cast(unsigned, v); }

#if __has_builtin(__builtin_amdgcn_fdot2)
__device__ __forceinline__ float dot2f(h2 a, h2 b, float c) {
  return __builtin_amdgcn_fdot2(a, b, c, false);
}
#else
__device__ __forceinline__ float dot2f(h2 a, h2 b, float c) {
  return c + (float)a.x * (float)b.x + (float)a.y * (float)b.y;
}
#endif

#if __has_builtin(__builtin_amdgcn_exp2f)
__device__ __forceinline__ float exp2_fast(float x) { return __builtin_amdgcn_exp2f(x); }
#else
__device__ __forceinline__ float exp2_fast(float x) { return exp2f(x); }
#endif
#if __has_builtin(__builtin_amdgcn_rcpf)
__device__ __forceinline__ float rcp_fast(float x) { return __builtin_amdgcn_rcpf(x); }
#else
__device__ __forceinline__ float rcp_fast(float x) { return 1.0f / x; }
#endif

__device__ __forceinline__ float sigm(float x) {
  return rcp_fast(1.0f + exp2_fast(-1.4426950408889634f * x));
}
__device__ __forceinline__ float tanh_fast(float x) {
  return 1.0f - 2.0f * rcp_fast(1.0f + exp2_fast(2.8853900817779268f * x));
}

// Coherent 16B load (bypass L1/L2, read L3). Caller MUST vm_drain() before use.
__device__ __forceinline__ uint4 coh_load16(const void* p) {
  uint4 v;
  asm volatile("global_load_dwordx4 %0, %1, off sc0 sc1"
               : "=v"(v) : "v"(p) : "memory");
  return v;
}
__device__ __forceinline__ void vm_drain() {
  asm volatile("s_waitcnt vmcnt(0)" ::: "memory");
}

// Sentinel = 0xFFFF per fp16 (a NaN). Legal h values are sigm*tanh in (-1,1)
// -> never NaN -> never 0xFFFF. A 16B chunk is valid when all 8 halves differ
// from the sentinel (halves are written by different threads, hence per-half).
__device__ __forceinline__ bool valid16(uint4 v) {
  return ((v.x & 0xFFFFu) != 0xFFFFu) && ((v.x >> 16) != 0xFFFFu) &&
         ((v.y & 0xFFFFu) != 0xFFFFu) && ((v.y >> 16) != 0xFFFFu) &&
         ((v.z & 0xFFFFu) != 0xFFFFu) && ((v.z >> 16) != 0xFFFFu) &&
         ((v.w & 0xFFFFu) != 0xFFFFu) && ((v.w >> 16) != 0xFFFFu);
}

// h store: 2B write-through to L3 (sc0 sc1) so data-polling consumers see it.
__device__ __forceinline__ void h_store(unsigned short* p, unsigned short v) {
  __hip_atomic_store(p, v, __ATOMIC_RELAXED, __HIP_MEMORY_SCOPE_AGENT);
}

// fill a region with the sentinel pattern (grid-stride, uint4 granularity)
__global__ __launch_bounds__(256) void fill_sent_k(uint4* __restrict__ dst, size_t n16) {
  uint4 s = {0xFFFFFFFFu, 0xFFFFFFFFu, 0xFFFFFFFFu, 0xFFFFFFFFu};
  size_t stride = (size_t)gridDim.x * 256;
  for (size_t i = (size_t)blockIdx.x * 256 + threadIdx.x; i < n16; i += stride)
    dst[i] = s;
}

// fp32 -> fp16 convert (4 elems/thread)
__global__ __launch_bounds__(256) void f2h_k(const float* __restrict__ src,
                                             _Float16* __restrict__ dst, int n4) {
  int i = blockIdx.x * 256 + threadIdx.x;
  if (i < n4) {
    float4 v = ((const float4*)src)[i];
    h4 o = {(_Float16)v.x, (_Float16)v.y, (_Float16)v.z, (_Float16)v.w};
    ((h4*)dst)[i] = o;
  }
}

// ---------------- persistent encoder: MFMA + sentinel dataflow sync ---------
// 512 blocks = 8 groups (dir x 4 batch-quarters of 8) x 64 blocks.
// Block: 8 h-cols x 4 gates; wave = gate. MFMA 16x16x32, A rows 8..15 zero.
// NO barriers: consumers poll h slots (write-once, sentinel-initialized).
__global__ __launch_bounds__(256, 1) void enc_coop_k(
    const _Float16* __restrict__ xh,
    const _Float16* __restrict__ WihF, const _Float16* __restrict__ WhhF, const float* __restrict__ bF,
    const _Float16* __restrict__ WihR, const _Float16* __restrict__ WhhR, const float* __restrict__ bR,
    float* __restrict__ cF, float* __restrict__ cR,
    _Float16* __restrict__ hsF, _Float16* __restrict__ hsR)
{
  __shared__ __align__(16) _Float16 cbuf[96][16][8];  // [k8][n][8]; n>=8 dead
  __shared__ float zfin[4][8][9];
  __shared__ float cls[8][9];

  const int bid = blockIdx.x;
  const int group = bid >> 6;       // 0..7 = dir*4 + quarter
  const int dir = group >> 2;
  const int q8 = (group & 3) << 3;  // batch base (8 batches per group)
  const int jb = bid & 63;
  const int c0 = jb << 3;           // 8 h-cols per block
  const int tid = threadIdx.x;
  const int lane = tid & 63;
  const int wv = tid >> 6;          // wave = gate 0..3

  const _Float16* __restrict__ Wih = dir ? WihR : WihF;
  const _Float16* __restrict__ Whh = dir ? WhhR : WhhF;
  const float* __restrict__ bias = dir ? bR : bF;
  _Float16* __restrict__ hs = dir ? hsR : hsF;
  float* __restrict__ cOut = dir ? cR : cF;

  for (int i = tid; i < 1536; i += 256) {   // zero cbuf (n>=8 cols stay zero)
    uint4 z = {0, 0, 0, 0};
    ((uint4*)cbuf)[i] = z;
  }

  // A-fragments: lane holds W'[row = c0 + (lane&15), gate wv][k-octet lane>>4]
  h8 aw[24];
  {
    const int m = lane & 15, kg = lane >> 4;
    const h8 zz = {0, 0, 0, 0, 0, 0, 0, 0};
    const int wrow = wv * H_ + c0 + (m & 7);
    const _Float16* wi = Wih + (size_t)wrow * D_;
    const _Float16* wh = Whh + (size_t)wrow * H_;
    #pragma unroll
    for (int tu = 0; tu < 24; ++tu) {
      int k = tu * 32 + kg * 8;
      h8 w = (k < 256) ? *(const h8*)(wi + k) : *(const h8*)(wh + (k - 256));
      aw[tu] = (m < 8) ? w : zz;
    }
  }

  const int cc = tid & 7, cb = tid >> 3;  // cell identity (tid<64)
  float bvg[4];
  #pragma unroll
  for (int g = 0; g < 4; ++g) bvg[g] = bias[g * H_ + c0 + cc];

  const char* cbase = (const char*)cbuf + (size_t)((lane >> 4) * 256 + (lane & 15) * 16);
  const int sn = tid & 7, k8b = (tid >> 3) * 3;   // staging: batch sn, 3 octets
  __syncthreads();

  for (int t = 0; t < S_; ++t) {
    const int xi = dir ? (S_ - 1 - t) : t;
    {  // ---- stage [x ; h_{t-1}]: x via cached loads, h via sentinel poll
      uint4 vs[3];
      unsigned pend = 0;
      #pragma unroll
      for (int u = 0; u < 3; ++u) {
        const int k8 = k8b + u;
        if (k8 < 32) {
          vs[u] = *(const uint4*)(xh + ((size_t)(q8 + sn) * S_ + xi) * D_ + k8 * 8);
        } else if (t == 0) {
          uint4 z = {0, 0, 0, 0};
          vs[u] = z;
        } else {
          pend |= 1u << u;
        }
      }
      if (pend) {
        const int xip = dir ? xi + 1 : xi - 1;
        const _Float16* hbase = hs + ((size_t)xip * B_ + q8 + sn) * H_;
        do {
          #pragma unroll
          for (int u = 0; u < 3; ++u)
            if (pend & (1u << u))
              vs[u] = coh_load16(hbase + (k8b + u - 32) * 8);
          vm_drain();
          #pragma unroll
          for (int u = 0; u < 3; ++u)
            if ((pend & (1u << u)) && valid16(vs[u])) pend &= ~(1u << u);
        } while (pend);
      }
      vm_drain();
      #pragma unroll
      for (int u = 0; u < 3; ++u) *(uint4*)&cbuf[k8b + u][sn][0] = vs[u];
    }
    __syncthreads();

    f32x4 acc = {0.f, 0.f, 0.f, 0.f};
    #pragma unroll
    for (int tu = 0; tu < 24; ++tu) {
      h8 bf = *(const h8*)(cbase + tu * 1024);
      acc = __builtin_amdgcn_mfma_f32_16x16x32_f16(aw[tu], bf, acc, 0, 0, 0);
    }
    {  // D: col(lane&15)=batch, row=(lane>>4)*4+r = block col; keep <8 only
      const int mrow = (lane >> 4) * 4, n = lane & 15;
      if (mrow < 8 && n < 8) {
        #pragma unroll
        for (int r = 0; r < 4; ++r) zfin[wv][mrow + r][n] = acc[r];
      }
    }
    __syncthreads();

    if (tid < 64) {  // cell: 8 cols x 8 batches
      const float zi = zfin[0][cc][cb] + bvg[0];
      const float zf = zfin[1][cc][cb] + bvg[1];
      const float zg = zfin[2][cc][cb] + bvg[2];
      const float zo = zfin[3][cc][cb] + bvg[3];
      const float c_old = (t == 0) ? 0.f : cls[cc][cb];
      const float cn = sigm(zf) * c_old + sigm(zi) * tanh_fast(zg);
      const float hn = sigm(zo) * tanh_fast(cn);
      cls[cc][cb] = cn;
      _Float16 hh = (_Float16)hn;
      h_store((unsigned short*)(hs + ((size_t)xi * B_ + q8 + cb) * H_ + c0 + cc),
              __builtin_bit_cast(unsigned short, hh));
      if (t == S_ - 1) cOut[(size_t)(q8 + cb) * H_ + c0 + cc] = cn;
    }
    // no barrier: next iteration's staging polls the data itself
  }
}

// ---------------- persistent decoder: MFMA + sentinel dataflow sync ---------
// 512 blocks = 8 groups (4 batches) x 64 blocks; block: 8 h-cols x 4 gates.
__global__ __launch_bounds__(256, 1) void dec_coop_k(
    const float* __restrict__ hd0, const float* __restrict__ cD0,
    const _Float16* __restrict__ Whh, const float* __restrict__ bias,
    _Float16* __restrict__ hdec)
{
  __shared__ __align__(16) _Float16 cbuf[64][16][8];  // [k8][n][8]; n>=4 dead
  __shared__ float zfin[4][8][5];
  __shared__ float cls[8][5];

  const int bid = blockIdx.x;
  const int group = bid >> 6;       // 0..7: batches group*4 .. +3
  const int g4 = group << 2;
  const int jb = bid & 63;
  const int c0 = jb << 3;
  const int tid = threadIdx.x;
  const int lane = tid & 63;
  const int wv = tid >> 6;

  for (int i = tid; i < 1024; i += 256) {
    uint4 z = {0, 0, 0, 0};
    ((uint4*)cbuf)[i] = z;
  }

  h8 aw[16];
  {
    const int m = lane & 15, kg = lane >> 4;
    const h8 zz = {0, 0, 0, 0, 0, 0, 0, 0};
    const _Float16* wh = Whh + (size_t)(wv * H_ + c0 + (m & 7)) * H_;
    #pragma unroll
    for (int tu = 0; tu < 16; ++tu) {
      h8 w = *(const h8*)(wh + tu * 32 + kg * 8);
      aw[tu] = (m < 8) ? w : zz;
    }
  }

  const int cc = tid & 7, cb = tid >> 3;  // cell identity (tid<32)
  float bvg[4];
  #pragma unroll
  for (int g = 0; g < 4; ++g) bvg[g] = bias[g * H_ + c0 + cc];
  if (tid < 32) cls[cc][cb] = cD0[(size_t)(g4 + cb) * H_ + c0 + cc];

  const char* cbase = (const char*)cbuf + (size_t)((lane >> 4) * 256 + (lane & 15) * 16);
  const int sn = tid & 3, k8 = tid >> 2;  // staging: batch sn, octet k8 (0..63)
  __syncthreads();

  for (int t = 0; t < S_; ++t) {
    {  // stage h_{t-1}: t=0 from hd0 (fp32), else sentinel-poll hdec[t-1]
      if (t == 0) {
        const float* src = hd0 + (size_t)(g4 + sn) * H_ + k8 * 8;
        float4 f0 = *(const float4*)src;
        float4 f1 = *(const float4*)(src + 4);
        h8 o = {(_Float16)f0.x, (_Float16)f0.y, (_Float16)f0.z, (_Float16)f0.w,
                (_Float16)f1.x, (_Float16)f1.y, (_Float16)f1.z, (_Float16)f1.w};
        *(h8*)&cbuf[k8][sn][0] = o;
      } else {
        const _Float16* src = hdec + ((size_t)(t - 1) * B_ + g4 + sn) * H_ + k8 * 8;
        uint4 v;
        do {
          v = coh_load16(src);
          vm_drain();
        } while (!valid16(v));
        *(uint4*)&cbuf[k8][sn][0] = v;
      }
    }
    __syncthreads();

    f32x4 acc = {0.f, 0.f, 0.f, 0.f};
    #pragma unroll
    for (int tu = 0; tu < 16; ++tu) {
      h8 bf = *(const h8*)(cbase + tu * 1024);
      acc = __builtin_amdgcn_mfma_f32_16x16x32_f16(aw[tu], bf, acc, 0, 0, 0);
    }
    {
      const int mrow = (lane >> 4) * 4, n = lane & 15;
      if (mrow < 8 && n < 4) {
        #pragma unroll
        for (int r = 0; r < 4; ++r) zfin[wv][mrow + r][n] = acc[r];
      }
    }
    __syncthreads();

    if (tid < 32) {  // cell: 8 cols x 4 batches
      const float zi = zfin[0][cc][cb] + bvg[0];
      const float zf = zfin[1][cc][cb] + bvg[1];
      const float zg = zfin[2][cc][cb] + bvg[2];
      const float zo = zfin[3][cc][cb] + bvg[3];
      const float cn = sigm(zf) * cls[cc][cb] + sigm(zi) * tanh_fast(zg);
      const float hn = sigm(zo) * tanh_fast(cn);
      cls[cc][cb] = cn;
      _Float16 hh = (_Float16)hn;
      h_store((unsigned short*)(hdec + ((size_t)t * B_ + g4 + cb) * H_ + c0 + cc),
              __builtin_bit_cast(unsigned short, hh));
    }
    // no barrier
  }
}

// ---------------- fp16 dot2 tiled GEMM: C[M,512] = op(A)@W^T + bias ----------
template <int MODE>
__global__ __launch_bounds__(256) void gemm_h_k(
    const _Float16* __restrict__ A1, const _Float16* __restrict__ A2,
    const _Float16* __restrict__ W, const float* __restrict__ bias,
    _Float16* __restrict__ C)
{
  __shared__ h2 As2[16][68];
  __shared__ h2 Bs2[16][68];
  const int tid = threadIdx.x;
  const int m0 = blockIdx.x * 64, n0 = blockIdx.y * 64;
  const int tn = tid & 15, tm = tid >> 4;
  float acc[4][4] = {};

  for (int kc = 0; kc < H_; kc += 32) {
    __syncthreads();
    {
      int mm = tid >> 2, q = tid & 3;
      uint4 a = *(const uint4*)(A1 + (size_t)(m0 + mm) * H_ + kc + q * 8);
      if (MODE == 1) {
        uint4 a2 = *(const uint4*)(A2 + (size_t)(m0 + mm) * H_ + kc + q * 8);
        a.x = U2(H2(a.x) + H2(a2.x)); a.y = U2(H2(a.y) + H2(a2.y));
        a.z = U2(H2(a.z) + H2(a2.z)); a.w = U2(H2(a.w) + H2(a2.w));
      }
      As2[q * 4 + 0][mm] = H2(a.x); As2[q * 4 + 1][mm] = H2(a.y);
      As2[q * 4 + 2][mm] = H2(a.z); As2[q * 4 + 3][mm] = H2(a.w);
      uint4 b = *(const uint4*)(W + (size_t)(n0 + mm) * H_ + kc + q * 8);
      Bs2[q * 4 + 0][mm] = H2(b.x); Bs2[q * 4 + 1][mm] = H2(b.y);
      Bs2[q * 4 + 2][mm] = H2(b.z); Bs2[q * 4 + 3][mm] = H2(b.w);
    }
    __syncthreads();
    #pragma unroll
    for (int k2 = 0; k2 < 16; ++k2) {
      uint4 au = *(const uint4*)&As2[k2][tm * 4];
      uint4 bu = *(const uint4*)&Bs2[k2][tn * 4];
      h2 a[4] = {H2(au.x), H2(au.y), H2(au.z), H2(au.w)};
      h2 b[4] = {H2(bu.x), H2(bu.y), H2(bu.z), H2(bu.w)};
      #pragma unroll
      for (int i = 0; i < 4; ++i)
        #pragma unroll
        for (int j = 0; j < 4; ++j)
          acc[i][j] = dot2f(a[i], b[j], acc[i][j]);
    }
  }
  float4 bl = *(const float4*)(bias + n0 + tn * 4);
  #pragma unroll
  for (int i = 0; i < 4; ++i) {
    h2 p0 = {(_Float16)(acc[i][0] + bl.x), (_Float16)(acc[i][1] + bl.y)};
    h2 p1 = {(_Float16)(acc[i][2] + bl.z), (_Float16)(acc[i][3] + bl.w)};
    uint2 st = {U2(p0), U2(p1)};
    *(uint2*)(C + (size_t)(m0 + tm * 4 + i) * H_ + n0 + tn * 4) = st;
  }
}

__device__ __forceinline__ float4 load4f(const float* p) { return *(const float4*)p; }
__device__ __forceinline__ float4 load4f(const _Float16* p) {
  uint2 u = *(const uint2*)p;
  h2 a = H2(u.x), b = H2(u.y);
  return make_float4((float)a.x, (float)a.y, (float)b.x, (float)b.y);
}

// small: C[32,512] = concat(A1,A2)@W^T + bias (K = 1024, halves of 512)
template <typename T>
__global__ __launch_bounds__(256) void gemm_cat_small_k(
    const T* __restrict__ A1, const T* __restrict__ A2,
    const float* __restrict__ W, const float* __restrict__ bias,
    float* __restrict__ C)
{
  const int tid = threadIdx.x;
  const int col = tid & 31;
  const int rg  = tid >> 5;
  const int n   = blockIdx.y * 32 + col;
  float acc[4] = {0, 0, 0, 0};
  #pragma unroll
  for (int pass = 0; pass < 2; ++pass) {
    const T* __restrict__ A = pass ? A2 : A1;
    const float4* __restrict__ w4 = (const float4*)(W + (size_t)n * 1024 + pass * 512);
    for (int k4 = 0; k4 < 128; ++k4) {
      float4 w = w4[k4];
      #pragma unroll
      for (int i = 0; i < 4; ++i) {
        int row = rg + (i << 3);
        float4 a = load4f(A + (size_t)row * H_ + k4 * 4);
        acc[i] += w.x * a.x + w.y * a.y + w.z * a.z + w.w * a.w;
      }
    }
  }
  const float bv = bias[n];
  #pragma unroll
  for (int i = 0; i < 4; ++i) {
    int row = rg + (i << 3);
    C[(size_t)row * H_ + n] = acc[i] + bv;
  }
}

// logits[b, t, s] = bvt + sum_h vt[h] * tanh(pre1[s,b,h] + Q[t,b,h])
__global__ __launch_bounds__(256) void attn_k(
    const _Float16* __restrict__ pre1, const _Float16* __restrict__ Qm,
    const float* __restrict__ vt, const float* __restrict__ bvt,
    float* __restrict__ out)
{
  __shared__ float sp[16][260];
  __shared__ float sq[16][260];
  __shared__ float sv[256];
  const int b = blockIdx.z, tbase = blockIdx.y << 4, sbase = blockIdx.x << 4;
  const int tid = threadIdx.x;
  const int so = tid & 15;
  const int to = tid >> 4;
  float acc = 0.f;

  for (int h0 = 0; h0 < H_; h0 += 256) {
    __syncthreads();
    {
      int i = tid >> 4, off = (tid & 15) * 16;
      uint4 q0 = *(const uint4*)(Qm + ((size_t)(tbase + i) * B_ + b) * H_ + h0 + off);
      uint4 q1 = *(const uint4*)(Qm + ((size_t)(tbase + i) * B_ + b) * H_ + h0 + off + 8);
      uint4 p0 = *(const uint4*)(pre1 + ((size_t)(sbase + i) * B_ + b) * H_ + h0 + off);
      uint4 p1 = *(const uint4*)(pre1 + ((size_t)(sbase + i) * B_ + b) * H_ + h0 + off + 8);
      const unsigned* qs = (const unsigned*)&q0;
      const unsigned* ps = (const unsigned*)&p0;
      #pragma unroll
      for (int u = 0; u < 4; ++u) {
        h2 qv = H2(qs[u]), pv = H2(ps[u]);
        sq[i][off + u * 2] = (float)qv.x; sq[i][off + u * 2 + 1] = (float)qv.y;
        sp[i][off + u * 2] = (float)pv.x; sp[i][off + u * 2 + 1] = (float)pv.y;
      }
      const unsigned* qs2 = (const unsigned*)&q1;
      const unsigned* ps2 = (const unsigned*)&p1;
      #pragma unroll
      for (int u = 0; u < 4; ++u) {
        h2 qv = H2(qs2[u]), pv = H2(ps2[u]);
        sq[i][off + 8 + u * 2] = (float)qv.x; sq[i][off + 8 + u * 2 + 1] = (float)qv.y;
        sp[i][off + 8 + u * 2] = (float)pv.x; sp[i][off + 8 + u * 2 + 1] = (float)pv.y;
      }
    }
    sv[tid] = vt[h0 + tid];
    __syncthreads();
    #pragma unroll 4
    for (int h = 0; h < 256; ++h)
      acc += sv[h] * tanh_fast(sp[so][h] + sq[to][h]);
  }
  out[((size_t)b * S_ + tbase + to) * S_ + sbase + so] = acc + bvt[0];
}

extern "C" void kernel_launch(void* const* d_in, const int* in_sizes, int n_in,
                              void* d_out, int out_size, void* d_ws, size_t ws_size,
                              hipStream_t stream)
{
  (void)in_sizes; (void)n_in; (void)out_size; (void)ws_size;
  const float* x     = (const float*)d_in[0];
  const float* WihF  = (const float*)d_in[1];
  const float* WhhF  = (const float*)d_in[2];
  const float* bF    = (const float*)d_in[3];
  const float* WihR  = (const float*)d_in[4];
  const float* WhhR  = (const float*)d_in[5];
  const float* bR    = (const float*)d_in[6];
  /* d_in[7] = Wih_d unused by reference decoder */
  const float* WhhD  = (const float*)d_in[8];
  const float* bD    = (const float*)d_in[9];
  const float* Wr_h  = (const float*)d_in[10];
  const float* br_h  = (const float*)d_in[11];
  const float* Wr_c  = (const float*)d_in[12];
  const float* br_c  = (const float*)d_in[13];
  const float* W1    = (const float*)d_in[14];
  const float* b1    = (const float*)d_in[15];
  const float* W2    = (const float*)d_in[16];
  const float* b2    = (const float*)d_in[17];
  const float* vt    = (const float*)d_in[18];
  const float* bvt   = (const float*)d_in[19];
  float* out = (float*)d_out;

  const size_t SBH = (size_t)S_ * B_ * H_;   // 8,388,608
  const size_t BH  = (size_t)B_ * H_;

  _Float16* hp = (_Float16*)d_ws;
  _Float16* hs_f  = hp;              hp += SBH;   // sentinel-filled
  _Float16* hs_r  = hp;              hp += SBH;   // sentinel-filled
  _Float16* hdec  = hp;              hp += SBH;   // sentinel-filled (un-aliased)
  _Float16* pre1h = hp;              hp += SBH;
  _Float16* Qmh   = hp;              hp += SBH;
  _Float16* xh    = hp;              hp += (size_t)B_ * S_ * D_;
  _Float16* wihF  = hp;              hp += (size_t)4 * H_ * D_;
  _Float16* wihR  = hp;              hp += (size_t)4 * H_ * D_;
  _Float16* whhF  = hp;              hp += (size_t)4 * H_ * H_;
  _Float16* whhR  = hp;              hp += (size_t)4 * H_ * H_;
  _Float16* whhD  = hp;              hp += (size_t)4 * H_ * H_;
  _Float16* w1h   = hp;              hp += (size_t)H_ * H_;
  _Float16* w2h   = hp;              hp += (size_t)H_ * H_;
  float* fp  = (float*)hp;
  float* cF  = fp;                   fp += BH;
  float* cR  = fp;                   fp += BH;
  float* cD  = fp;                   fp += BH;
  float* hd0 = fp;                   fp += BH;

  // sentinel-fill the three h-exchange buffers (3*SBH halves = 48 MB)
  fill_sent_k<<<2048, 256, 0, stream>>>((uint4*)hs_f, 3 * SBH / 8);

  // fp32 -> fp16 converts
  f2h_k<<<(B_ * S_ * D_ / 4 + 255) / 256, 256, 0, stream>>>(x, xh, B_ * S_ * D_ / 4);
  f2h_k<<<(4 * H_ * D_ / 4 + 255) / 256, 256, 0, stream>>>(WihF, wihF, 4 * H_ * D_ / 4);
  f2h_k<<<(4 * H_ * D_ / 4 + 255) / 256, 256, 0, stream>>>(WihR, wihR, 4 * H_ * D_ / 4);
  f2h_k<<<(4 * H_ * H_ / 4 + 255) / 256, 256, 0, stream>>>(WhhF, whhF, 4 * H_ * H_ / 4);
  f2h_k<<<(4 * H_ * H_ / 4 + 255) / 256, 256, 0, stream>>>(WhhR, whhR, 4 * H_ * H_ / 4);
  f2h_k<<<(4 * H_ * H_ / 4 + 255) / 256, 256, 0, stream>>>(WhhD, whhD, 4 * H_ * H_ / 4);
  f2h_k<<<(H_ * H_ / 4 + 255) / 256, 256, 0, stream>>>(W1, w1h, H_ * H_ / 4);
  f2h_k<<<(H_ * H_ / 4 + 255) / 256, 256, 0, stream>>>(W2, w2h, H_ * H_ / 4);

  // encoder: persistent MFMA, sentinel dataflow sync
  enc_coop_k<<<512, 256, 0, stream>>>(xh, wihF, whhF, bF, wihR, whhR, bR,
                                      cF, cR, hs_f, hs_r);

  // decoder init
  gemm_cat_small_k<_Float16><<<dim3(1, 16), 256, 0, stream>>>(
      hs_f + (size_t)(S_ - 1) * BH, hs_r, Wr_h, br_h, hd0);
  gemm_cat_small_k<float><<<dim3(1, 16), 256, 0, stream>>>(cF, cR, Wr_c, br_c, cD);

  // pre1 = (hs_f + hs_r) @ W1^T + b1
  gemm_h_k<1><<<dim3(256, 8), 256, 0, stream>>>(hs_f, hs_r, w1h, b1, pre1h);

  // decoder: persistent MFMA, sentinel dataflow sync
  dec_coop_k<<<512, 256, 0, stream>>>(hd0, cD, whhD, bD, hdec);

  // Q = Hdec @ W2^T + b2
  gemm_h_k<0><<<dim3(256, 8), 256, 0, stream>>>(hdec, nullptr, w2h, b2, Qmh);

  // attention
  attn_k<<<dim3(32, 32, 32), 256, 0, stream>>>(pre1h, Qmh, vt, bvt, out);
}